// Round 1
// baseline (603.918 us; speedup 1.0000x reference)
//
#include <hip/hip_runtime.h>
#include <hip/hip_bf16.h>
#include <stdint.h>

#define BATCH 8192
#define NSTATE 30
#define DIN 13
#define E1 256
#define E2 128

__device__ __forceinline__ float bf2f(__hip_bfloat16 x) { return __bfloat162float(x); }

// ---------------------------------------------------------------------------
// k_prep: build combined weight matrices in workspace.
//   Mh = c1_rootW[0]+[4]+[6] - c1_relW[6]           (128x32)
//   Mo = c1_rootW[3]+[5]+[7] - c1_relW[7]           (128x32)
//   Wcat (384x96): U=[er|sh|so] -> [pre_r|ch|co]
//   Wc2  (96x128): V=[xr|sh2|so2] -> hr_pre
// ---------------------------------------------------------------------------
__global__ void k_prep(const float* __restrict__ c1_relW, const float* __restrict__ c1_relb,
                       const float* __restrict__ c1_rootW,
                       const float* __restrict__ c2_relW, const float* __restrict__ c2_relb,
                       const float* __restrict__ c2_rootW,
                       float* __restrict__ Mh, float* __restrict__ Mo,
                       float* __restrict__ Wcat, float* __restrict__ bcat,
                       float* __restrict__ Wc2, float* __restrict__ bc2)
{
    int gid = blockIdx.x * blockDim.x + threadIdx.x;
    int gsz = gridDim.x * blockDim.x;
    for (int i = gid; i < 4096; i += gsz) {
        Mh[i] = c1_rootW[i] + c1_rootW[4*4096 + i] + c1_rootW[6*4096 + i] - c1_relW[6*4096 + i];
        Mo[i] = c1_rootW[3*4096 + i] + c1_rootW[5*4096 + i] + c1_rootW[7*4096 + i] - c1_relW[7*4096 + i];
    }
    for (int i = gid; i < 384 * 96; i += gsz) {
        int k = i / 96, m = i - (i / 96) * 96;
        int part = k >> 7, c = k & 127;
        int grp = m >> 5, mm = m & 31;
        int off = c * 32 + mm;
        float v;
        if (part == 0) {       // er source
            v = (grp == 0) ? (c1_rootW[4096 + off] + c1_rootW[8192 + off])
              : (grp == 1) ? c1_relW[off]                  // relW[0]
                           : c1_relW[3*4096 + off];        // relW[3]
        } else if (part == 1) { // sh source
            v = (grp == 0) ? c1_relW[1*4096 + off]
              : (grp == 1) ? c1_relW[6*4096 + off]
                           : c1_relW[5*4096 + off];
        } else {                // so source
            v = (grp == 0) ? c1_relW[2*4096 + off]
              : (grp == 1) ? c1_relW[4*4096 + off]
                           : c1_relW[7*4096 + off];
        }
        Wcat[i] = v;
    }
    for (int i = gid; i < 96; i += gsz) {
        int grp = i >> 5, mm = i & 31;
        float v;
        if (grp == 0)      v = c1_relb[32 + mm] + c1_relb[64 + mm];
        else if (grp == 1) v = c1_relb[mm] + c1_relb[128 + mm] + c1_relb[192 + mm];
        else               v = c1_relb[96 + mm] + c1_relb[160 + mm] + c1_relb[224 + mm];
        bcat[i] = v;
    }
    for (int i = gid; i < 96 * 128; i += gsz) {
        int k = i >> 7, n = i & 127;
        int grp = k >> 5, kk = k & 31;
        int off = kk * 128 + n;
        float v;
        if (grp == 0)      v = c2_rootW[4096 + off] + c2_rootW[8192 + off];
        else if (grp == 1) v = c2_relW[4096 + off];
        else               v = c2_relW[8192 + off];
        Wc2[i] = v;
    }
    for (int i = gid; i < 128; i += gsz) bc2[i] = c2_relb[128 + i] + c2_relb[256 + i];
}

// ---------------------------------------------------------------------------
// k_mlp: fused 2-layer MLP e = relu(relu(X@W0+b0)@W1+b1) for 32 rows/block.
// Writes e transposed [col 0..127][row] as bf16.
// ---------------------------------------------------------------------------
template<int NPB, int NODE0, int INOFF, int INDIM>
__global__ __launch_bounds__(256) void k_mlp(
    const float* __restrict__ state,
    const float* __restrict__ W0, const float* __restrict__ b0,
    const float* __restrict__ W1, const float* __restrict__ b1,
    __hip_bfloat16* __restrict__ eT, int NR)
{
    __shared__ float Xs[8][36];
    __shared__ float hs[E1][36];
    __shared__ __hip_bfloat16 es[E2][40];

    const int t = threadIdx.x;
    const int row0 = blockIdx.x * 32;

    { // stage X: [in_dim][32 rows]
        int j = t >> 5, r = t & 31;
        float v = 0.f;
        if (j < INDIM) {
            int row = row0 + r;
            int b = row / NPB;
            int n = row - b * NPB + NODE0;
            v = state[((size_t)b * NSTATE + n) * DIN + INOFF + j];
        }
        Xs[j][r] = v;
    }
    __syncthreads();

    { // layer 1: thread t owns hidden column t for all 32 rows
        float a[32];
        float bias = b0[t];
        #pragma unroll
        for (int r = 0; r < 32; ++r) a[r] = bias;
        #pragma unroll
        for (int j = 0; j < INDIM; ++j) {
            float w = W0[j * E1 + t];
            #pragma unroll
            for (int r = 0; r < 32; ++r) a[r] = fmaf(Xs[j][r], w, a[r]);
        }
        #pragma unroll
        for (int r = 0; r < 32; r += 4) {
            float4 v;
            v.x = fmaxf(a[r], 0.f);   v.y = fmaxf(a[r+1], 0.f);
            v.z = fmaxf(a[r+2], 0.f); v.w = fmaxf(a[r+3], 0.f);
            *(float4*)&hs[t][r] = v;
        }
    }
    __syncthreads();

    // layer 2: register tile 4 rows x 4 cols per thread
    const int rg = t >> 5, cg = t & 31;
    const int r0 = rg * 4, c0 = cg * 4;
    float acc[4][4];
    {
        float4 bb = *(const float4*)&b1[c0];
        #pragma unroll
        for (int i = 0; i < 4; ++i) { acc[i][0]=bb.x; acc[i][1]=bb.y; acc[i][2]=bb.z; acc[i][3]=bb.w; }
    }
    #pragma unroll 4
    for (int k = 0; k < E1; ++k) {
        float4 hv = *(const float4*)&hs[k][r0];
        float4 wv = *(const float4*)&W1[k * E2 + c0];
        float hvf[4] = {hv.x, hv.y, hv.z, hv.w};
        float wvf[4] = {wv.x, wv.y, wv.z, wv.w};
        #pragma unroll
        for (int i = 0; i < 4; ++i)
            #pragma unroll
            for (int j = 0; j < 4; ++j)
                acc[i][j] = fmaf(hvf[i], wvf[j], acc[i][j]);
    }
    // epilogue: relu -> bf16, transpose through LDS for coalesced global writes
    #pragma unroll
    for (int j = 0; j < 4; ++j)
        #pragma unroll
        for (int i = 0; i < 4; ++i)
            es[c0 + j][r0 + i] = __float2bfloat16(fmaxf(acc[i][j], 0.f));
    __syncthreads();
    {
        int c = t >> 1, hf = t & 1;
        const uint4* src = (const uint4*)&es[c][hf * 16];
        uint4 v0 = src[0], v1 = src[1];
        uint4* dst = (uint4*)(eT + (size_t)c * NR + row0 + hf * 16);
        dst[0] = v0; dst[1] = v1;
    }
}

// ---------------------------------------------------------------------------
// k_red: sh[b] = sum_n eh[b,n], so[b] = sum_n eo[b,n]  (feature-major out)
// ---------------------------------------------------------------------------
__global__ __launch_bounds__(256) void k_red(const __hip_bfloat16* __restrict__ eTh,
                                             const __hip_bfloat16* __restrict__ eTo,
                                             float* __restrict__ shT, float* __restrict__ soT)
{
    int gid = blockIdx.x * 256 + threadIdx.x;   // 128*8192 total
    int b = gid & (BATCH - 1);
    int c = gid >> 13;
    const __hip_bfloat16* ph = eTh + (size_t)c * (BATCH * 20) + b * 20;
    float s = 0.f;
    #pragma unroll
    for (int n = 0; n < 20; ++n) s += bf2f(ph[n]);
    shT[(size_t)c * BATCH + b] = s;
    const __hip_bfloat16* po = eTo + (size_t)c * (BATCH * 10) + b * 10;
    float s2 = 0.f;
    #pragma unroll
    for (int n = 0; n < 10; ++n) s2 += bf2f(po[n]);
    soT[(size_t)c * BATCH + b] = s2;
}

// ---------------------------------------------------------------------------
// k_u: [pre_r|ch|co](96) = U(384) @ Wcat + bcat ; xr = relu(pre_r)
// ---------------------------------------------------------------------------
__global__ __launch_bounds__(128) void k_u(
    const __hip_bfloat16* __restrict__ eTr,
    const float* __restrict__ shT, const float* __restrict__ soT,
    const float* __restrict__ Wcat, const float* __restrict__ bcat,
    float* __restrict__ xrT, float* __restrict__ chT, float* __restrict__ coT)
{
    __shared__ float U[384][36];
    const int t = threadIdx.x;
    const int b0 = blockIdx.x * 32;
    for (int idx = t; idx < 384 * 32; idx += 128) {
        int k = idx >> 5, bl = idx & 31;
        float v;
        if (k < 128)      v = bf2f(eTr[(size_t)k * BATCH + b0 + bl]);
        else if (k < 256) v = shT[(size_t)(k - 128) * BATCH + b0 + bl];
        else              v = soT[(size_t)(k - 256) * BATCH + b0 + bl];
        U[k][bl] = v;
    }
    __syncthreads();
    if (t < 96) {
        float acc[32];
        #pragma unroll
        for (int i = 0; i < 32; ++i) acc[i] = 0.f;
        for (int k = 0; k < 384; ++k) {
            float w = Wcat[k * 96 + t];
            #pragma unroll
            for (int i = 0; i < 32; i += 4) {
                float4 u = *(const float4*)&U[k][i];
                acc[i]   = fmaf(u.x, w, acc[i]);
                acc[i+1] = fmaf(u.y, w, acc[i+1]);
                acc[i+2] = fmaf(u.z, w, acc[i+2]);
                acc[i+3] = fmaf(u.w, w, acc[i+3]);
            }
        }
        float bias = bcat[t];
        if (t < 32) {
            float* dst = xrT + (size_t)t * BATCH + b0;
            #pragma unroll
            for (int i = 0; i < 32; ++i) dst[i] = fmaxf(acc[i] + bias, 0.f);
        } else if (t < 64) {
            float* dst = chT + (size_t)(t - 32) * BATCH + b0;
            #pragma unroll
            for (int i = 0; i < 32; ++i) dst[i] = acc[i] + bias;
        } else {
            float* dst = coT + (size_t)(t - 64) * BATCH + b0;
            #pragma unroll
            for (int i = 0; i < 32; ++i) dst[i] = acc[i] + bias;
        }
    }
}

// ---------------------------------------------------------------------------
// k_t: s2[b][m] = sum_n relu(cT[b][m] + e[b,n] @ M[:,m]); 160 rows/block
// ---------------------------------------------------------------------------
template<int NPB>
__global__ __launch_bounds__(256) void k_t(
    const __hip_bfloat16* __restrict__ eT, int NR,
    const float* __restrict__ M, const float* __restrict__ cT,
    float* __restrict__ s2T)
{
    __shared__ float Ml[128][32];
    __shared__ float el[32][164];
    __shared__ float s2l[16][33];
    const int t = threadIdx.x;
    const int m = t & 31, rg = t >> 5;      // 8 row-groups x 20 rows
    const int row0 = blockIdx.x * 160;
    for (int idx = t; idx < 4096; idx += 256) Ml[idx >> 5][idx & 31] = M[idx];
    float acc[20];
    #pragma unroll
    for (int i = 0; i < 20; ++i) acc[i] = 0.f;
    for (int kc = 0; kc < 128; kc += 32) {
        __syncthreads();
        for (int idx = t; idx < 32 * 160; idx += 256) {
            int kk = idx / 160;
            int r = idx - kk * 160;
            el[kk][r] = bf2f(eT[(size_t)(kc + kk) * NR + row0 + r]);
        }
        __syncthreads();
        #pragma unroll 4
        for (int kk = 0; kk < 32; ++kk) {
            float mh = Ml[kc + kk][m];
            const float* ep = &el[kk][rg * 20];
            #pragma unroll
            for (int q = 0; q < 5; ++q) {
                float4 e4 = *(const float4*)(ep + q * 4);
                acc[q*4]   = fmaf(e4.x, mh, acc[q*4]);
                acc[q*4+1] = fmaf(e4.y, mh, acc[q*4+1]);
                acc[q*4+2] = fmaf(e4.z, mh, acc[q*4+2]);
                acc[q*4+3] = fmaf(e4.w, mh, acc[q*4+3]);
            }
        }
    }
    constexpr int BS = 160 / NPB;    // b's per block (8 or 16)
    constexpr int BPRG = 20 / NPB;   // b's per row-group (1 or 2)
    #pragma unroll
    for (int bb = 0; bb < BPRG; ++bb) {
        int bl = rg * BPRG + bb;
        int b = blockIdx.x * BS + bl;
        float chv = cT[(size_t)m * BATCH + b];
        float s = 0.f;
        #pragma unroll
        for (int i = 0; i < NPB; ++i) s += fmaxf(chv + acc[bb * NPB + i], 0.f);
        s2l[bl][m] = s;
    }
    __syncthreads();
    for (int idx = t; idx < 32 * BS; idx += 256) {
        int mm = idx / BS, bl = idx - mm * BS;
        s2T[(size_t)mm * BATCH + blockIdx.x * BS + bl] = s2l[bl][mm];
    }
}

// ---------------------------------------------------------------------------
// k_c2: hr = relu(V(96) @ Wc2 + bc2), 32 b per block
// ---------------------------------------------------------------------------
__global__ __launch_bounds__(256) void k_c2(
    const float* __restrict__ xrT, const float* __restrict__ sh2T, const float* __restrict__ so2T,
    const float* __restrict__ Wc2, const float* __restrict__ bc2,
    float* __restrict__ hrT)
{
    __shared__ float V[96][36];
    const int t = threadIdx.x;
    const int b0 = blockIdx.x * 32;
    for (int idx = t; idx < 96 * 32; idx += 256) {
        int k = idx >> 5, bl = idx & 31;
        float v;
        if (k < 32)      v = xrT[(size_t)k * BATCH + b0 + bl];
        else if (k < 64) v = sh2T[(size_t)(k - 32) * BATCH + b0 + bl];
        else             v = so2T[(size_t)(k - 64) * BATCH + b0 + bl];
        V[k][bl] = v;
    }
    __syncthreads();
    const int n = t & 127, bg = t >> 7;
    float acc[16];
    #pragma unroll
    for (int i = 0; i < 16; ++i) acc[i] = 0.f;
    for (int k = 0; k < 96; ++k) {
        float w = Wc2[k * 128 + n];
        #pragma unroll
        for (int i = 0; i < 16; i += 4) {
            float4 u = *(const float4*)&V[k][bg * 16 + i];
            acc[i]   = fmaf(u.x, w, acc[i]);
            acc[i+1] = fmaf(u.y, w, acc[i+1]);
            acc[i+2] = fmaf(u.z, w, acc[i+2]);
            acc[i+3] = fmaf(u.w, w, acc[i+3]);
        }
    }
    float bias = bc2[n];
    float* dst = hrT + (size_t)n * BATCH + b0 + bg * 16;
    #pragma unroll
    for (int i = 0; i < 16; ++i) dst[i] = fmaxf(acc[i] + bias, 0.f);
}

// ---------------------------------------------------------------------------
// k_v1: v1 = relu(hr(128) @ vW0 + vb0) -> 256 cols, 32 b per block
// ---------------------------------------------------------------------------
__global__ __launch_bounds__(256) void k_v1(
    const float* __restrict__ hrT, const float* __restrict__ W, const float* __restrict__ bias_,
    float* __restrict__ v1T)
{
    __shared__ float A[128][36];
    const int t = threadIdx.x;
    const int b0 = blockIdx.x * 32;
    for (int idx = t; idx < 128 * 32; idx += 256) {
        int k = idx >> 5, bl = idx & 31;
        A[k][bl] = hrT[(size_t)k * BATCH + b0 + bl];
    }
    __syncthreads();
    float acc[32];
    #pragma unroll
    for (int i = 0; i < 32; ++i) acc[i] = 0.f;
    for (int k = 0; k < 128; ++k) {
        float w = W[k * 256 + t];
        #pragma unroll
        for (int i = 0; i < 32; i += 4) {
            float4 u = *(const float4*)&A[k][i];
            acc[i]   = fmaf(u.x, w, acc[i]);
            acc[i+1] = fmaf(u.y, w, acc[i+1]);
            acc[i+2] = fmaf(u.z, w, acc[i+2]);
            acc[i+3] = fmaf(u.w, w, acc[i+3]);
        }
    }
    float bv = bias_[t];
    float* dst = v1T + (size_t)t * BATCH + b0;
    #pragma unroll
    for (int i = 0; i < 32; ++i) dst[i] = fmaxf(acc[i] + bv, 0.f);
}

// ---------------------------------------------------------------------------
// k_v2: v2 = relu(v1(256) @ vW1 + vb1) -> 128 cols, 32 b per block
// ---------------------------------------------------------------------------
__global__ __launch_bounds__(256) void k_v2(
    const float* __restrict__ v1T, const float* __restrict__ W, const float* __restrict__ bias_,
    float* __restrict__ v2T)
{
    __shared__ float A[256][36];
    const int t = threadIdx.x;
    const int b0 = blockIdx.x * 32;
    for (int idx = t; idx < 256 * 32; idx += 256) {
        int k = idx >> 5, bl = idx & 31;
        A[k][bl] = v1T[(size_t)k * BATCH + b0 + bl];
    }
    __syncthreads();
    const int n = t & 127, bg = t >> 7;
    float acc[16];
    #pragma unroll
    for (int i = 0; i < 16; ++i) acc[i] = 0.f;
    for (int k = 0; k < 256; ++k) {
        float w = W[k * 128 + n];
        #pragma unroll
        for (int i = 0; i < 16; i += 4) {
            float4 u = *(const float4*)&A[k][bg * 16 + i];
            acc[i]   = fmaf(u.x, w, acc[i]);
            acc[i+1] = fmaf(u.y, w, acc[i+1]);
            acc[i+2] = fmaf(u.z, w, acc[i+2]);
            acc[i+3] = fmaf(u.w, w, acc[i+3]);
        }
    }
    float bv = bias_[n];
    float* dst = v2T + (size_t)n * BATCH + b0 + bg * 16;
    #pragma unroll
    for (int i = 0; i < 16; ++i) dst[i] = fmaxf(acc[i] + bv, 0.f);
}

// ---------------------------------------------------------------------------
// k_v3: out[b] = v2[b] . vW2 + vb2
// ---------------------------------------------------------------------------
__global__ __launch_bounds__(256) void k_v3(
    const float* __restrict__ v2T, const float* __restrict__ W2, const float* __restrict__ b2,
    float* __restrict__ out)
{
    int b = blockIdx.x * 256 + threadIdx.x;
    float acc = b2[0];
    for (int k = 0; k < 128; ++k)
        acc = fmaf(v2T[(size_t)k * BATCH + b], W2[k], acc);
    out[b] = acc;
}

// ---------------------------------------------------------------------------
extern "C" void kernel_launch(void* const* d_in, const int* in_sizes, int n_in,
                              void* d_out, int out_size, void* d_ws, size_t ws_size,
                              hipStream_t stream)
{
    const float* state   = (const float*)d_in[0];
    const float* wr_W0   = (const float*)d_in[2];
    const float* wr_b0   = (const float*)d_in[3];
    const float* wr_W1   = (const float*)d_in[4];
    const float* wr_b1   = (const float*)d_in[5];
    const float* wh_W0   = (const float*)d_in[6];
    const float* wh_b0   = (const float*)d_in[7];
    const float* wh_W1   = (const float*)d_in[8];
    const float* wh_b1   = (const float*)d_in[9];
    const float* wo_W0   = (const float*)d_in[10];
    const float* wo_b0   = (const float*)d_in[11];
    const float* wo_W1   = (const float*)d_in[12];
    const float* wo_b1   = (const float*)d_in[13];
    const float* c1_relW = (const float*)d_in[14];
    const float* c1_relb = (const float*)d_in[15];
    const float* c1_rootW= (const float*)d_in[16];
    const float* c2_relW = (const float*)d_in[17];
    const float* c2_relb = (const float*)d_in[18];
    const float* c2_rootW= (const float*)d_in[19];
    const float* v_W0    = (const float*)d_in[20];
    const float* v_b0    = (const float*)d_in[21];
    const float* v_W1    = (const float*)d_in[22];
    const float* v_b1    = (const float*)d_in[23];
    const float* v_W2    = (const float*)d_in[24];
    const float* v_b2    = (const float*)d_in[25];

    char* ws = (char*)d_ws;
    size_t off = 0;
    auto alloc = [&](size_t bytes) -> char* {
        char* p = ws + off;
        off = (off + bytes + 255) & ~(size_t)255;
        return p;
    };
    __hip_bfloat16* eTh = (__hip_bfloat16*)alloc((size_t)128 * 163840 * 2);
    __hip_bfloat16* eTo = (__hip_bfloat16*)alloc((size_t)128 * 81920 * 2);
    __hip_bfloat16* eTr = (__hip_bfloat16*)alloc((size_t)128 * 8192 * 2);
    float* shT  = (float*)alloc((size_t)128 * 8192 * 4);
    float* soT  = (float*)alloc((size_t)128 * 8192 * 4);
    float* xrT  = (float*)alloc((size_t)32 * 8192 * 4);
    float* chT  = (float*)alloc((size_t)32 * 8192 * 4);
    float* coT  = (float*)alloc((size_t)32 * 8192 * 4);
    float* sh2T = (float*)alloc((size_t)32 * 8192 * 4);
    float* so2T = (float*)alloc((size_t)32 * 8192 * 4);
    float* hrT  = (float*)alloc((size_t)128 * 8192 * 4);
    float* v1T  = (float*)alloc((size_t)256 * 8192 * 4);
    float* v2T  = (float*)alloc((size_t)128 * 8192 * 4);
    float* Mh   = (float*)alloc(4096 * 4);
    float* Mo   = (float*)alloc(4096 * 4);
    float* Wcat = (float*)alloc(36864 * 4);
    float* bcat = (float*)alloc(96 * 4);
    float* Wc2  = (float*)alloc(12288 * 4);
    float* bc2  = (float*)alloc(128 * 4);
    (void)ws_size; (void)in_sizes; (void)n_in; (void)out_size;

    k_prep<<<64, 256, 0, stream>>>(c1_relW, c1_relb, c1_rootW, c2_relW, c2_relb, c2_rootW,
                                   Mh, Mo, Wcat, bcat, Wc2, bc2);
    k_mlp<20, 0, 6, 7><<<5120, 256, 0, stream>>>(state, wh_W0, wh_b0, wh_W1, wh_b1, eTh, 163840);
    k_mlp<10, 20, 6, 7><<<2560, 256, 0, stream>>>(state, wo_W0, wo_b0, wo_W1, wo_b1, eTo, 81920);
    k_mlp<1, 0, 0, 6><<<256, 256, 0, stream>>>(state, wr_W0, wr_b0, wr_W1, wr_b1, eTr, 8192);
    k_red<<<4096, 256, 0, stream>>>(eTh, eTo, shT, soT);
    k_u<<<256, 128, 0, stream>>>(eTr, shT, soT, Wcat, bcat, xrT, chT, coT);
    k_t<20><<<1024, 256, 0, stream>>>(eTh, 163840, Mh, chT, sh2T);
    k_t<10><<<512, 256, 0, stream>>>(eTo, 81920, Mo, coT, so2T);
    k_c2<<<256, 256, 0, stream>>>(xrT, sh2T, so2T, Wc2, bc2, hrT);
    k_v1<<<256, 256, 0, stream>>>(hrT, v_W0, v_b0, v1T);
    k_v2<<<256, 256, 0, stream>>>(v1T, v_W1, v_b1, v2T);
    k_v3<<<32, 256, 0, stream>>>(v2T, v_W2, v_b2, (float*)d_out);
}

// Round 3
// 427.259 us; speedup vs baseline: 1.4135x; 1.4135x over previous
//
#include <hip/hip_runtime.h>
#include <hip/hip_bf16.h>
#include <stdint.h>

#define BATCH 8192
#define NSTATE 30
#define DIN 13
#define E1 256
#define E2 128

typedef short bf16x8 __attribute__((ext_vector_type(8)));
typedef float f32x4 __attribute__((ext_vector_type(4)));

__device__ __forceinline__ float bf2f(__hip_bfloat16 x) { return __bfloat162float(x); }

// f32 -> bf16 bits, round-to-nearest-even
__device__ __forceinline__ unsigned short f2b(float f) {
    unsigned u = __float_as_uint(f);
    u += 0x7FFFu + ((u >> 16) & 1u);
    return (unsigned short)(u >> 16);
}

// ---------------------------------------------------------------------------
// k_prep: build combined weight matrices + bf16 MFMA fragment weights.
//   Mh = c1_rootW[0]+[4]+[6] - c1_relW[6]           (128x32)
//   Mo = c1_rootW[3]+[5]+[7] - c1_relW[7]           (128x32)
//   Wcat (384x96): U=[er|sh|so] -> [pre_r|ch|co]
//   Wc2  (96x128): V=[xr|sh2|so2] -> hr_pre
//   W0b_* [256 n][8 k] bf16 (k zero-padded past INDIM)
//   W1f_* [(ks*8+nt)*64+lane][8] bf16 B-fragments, ks=0..7 -> 32768 entries
// ---------------------------------------------------------------------------
__global__ void k_prep(const float* __restrict__ c1_relW, const float* __restrict__ c1_relb,
                       const float* __restrict__ c1_rootW,
                       const float* __restrict__ c2_relW, const float* __restrict__ c2_relb,
                       const float* __restrict__ c2_rootW,
                       const float* __restrict__ wh_W0, const float* __restrict__ wh_W1,
                       const float* __restrict__ wo_W0, const float* __restrict__ wo_W1,
                       const float* __restrict__ wr_W0, const float* __restrict__ wr_W1,
                       float* __restrict__ Mh, float* __restrict__ Mo,
                       float* __restrict__ Wcat, float* __restrict__ bcat,
                       float* __restrict__ Wc2, float* __restrict__ bc2,
                       unsigned short* __restrict__ W0b_h, unsigned short* __restrict__ W0b_o,
                       unsigned short* __restrict__ W0b_r,
                       unsigned short* __restrict__ W1f_h, unsigned short* __restrict__ W1f_o,
                       unsigned short* __restrict__ W1f_r)
{
    int gid = blockIdx.x * blockDim.x + threadIdx.x;
    int gsz = gridDim.x * blockDim.x;
    for (int i = gid; i < 4096; i += gsz) {
        Mh[i] = c1_rootW[i] + c1_rootW[4*4096 + i] + c1_rootW[6*4096 + i] - c1_relW[6*4096 + i];
        Mo[i] = c1_rootW[3*4096 + i] + c1_rootW[5*4096 + i] + c1_rootW[7*4096 + i] - c1_relW[7*4096 + i];
    }
    for (int i = gid; i < 384 * 96; i += gsz) {
        int k = i / 96, m = i - (i / 96) * 96;
        int part = k >> 7, c = k & 127;
        int grp = m >> 5, mm = m & 31;
        int off = c * 32 + mm;
        float v;
        if (part == 0) {
            v = (grp == 0) ? (c1_rootW[4096 + off] + c1_rootW[8192 + off])
              : (grp == 1) ? c1_relW[off]
                           : c1_relW[3*4096 + off];
        } else if (part == 1) {
            v = (grp == 0) ? c1_relW[1*4096 + off]
              : (grp == 1) ? c1_relW[6*4096 + off]
                           : c1_relW[5*4096 + off];
        } else {
            v = (grp == 0) ? c1_relW[2*4096 + off]
              : (grp == 1) ? c1_relW[4*4096 + off]
                           : c1_relW[7*4096 + off];
        }
        Wcat[i] = v;
    }
    for (int i = gid; i < 96; i += gsz) {
        int grp = i >> 5, mm = i & 31;
        float v;
        if (grp == 0)      v = c1_relb[32 + mm] + c1_relb[64 + mm];
        else if (grp == 1) v = c1_relb[mm] + c1_relb[128 + mm] + c1_relb[192 + mm];
        else               v = c1_relb[96 + mm] + c1_relb[160 + mm] + c1_relb[224 + mm];
        bcat[i] = v;
    }
    for (int i = gid; i < 96 * 128; i += gsz) {
        int k = i >> 7, n = i & 127;
        int grp = k >> 5, kk = k & 31;
        int off = kk * 128 + n;
        float v;
        if (grp == 0)      v = c2_rootW[4096 + off] + c2_rootW[8192 + off];
        else if (grp == 1) v = c2_relW[4096 + off];
        else               v = c2_relW[8192 + off];
        Wc2[i] = v;
    }
    for (int i = gid; i < 128; i += gsz) bc2[i] = c2_relb[128 + i] + c2_relb[256 + i];

    // bf16 layer-1 weights, fragment-padded to k=8
    for (int i = gid; i < 2048; i += gsz) {
        int n = i >> 3, j = i & 7;
        W0b_h[i] = (j < 7) ? f2b(wh_W0[j * 256 + n]) : 0;
        W0b_o[i] = (j < 7) ? f2b(wo_W0[j * 256 + n]) : 0;
        W0b_r[i] = (j < 6) ? f2b(wr_W0[j * 256 + n]) : 0;
    }
    // bf16 layer-2 weights in per-lane B-fragment order (FULL 32768 entries)
    for (int i = gid; i < 32768; i += gsz) {
        int j = i & 7, l = (i >> 3) & 63, nt = (i >> 9) & 7, ks = i >> 12;
        int k = ks * 32 + (l >> 4) * 8 + j;
        int n = nt * 16 + (l & 15);
        W1f_h[i] = f2b(wh_W1[k * 128 + n]);
        W1f_o[i] = f2b(wo_W1[k * 128 + n]);
        W1f_r[i] = f2b(wr_W1[k * 128 + n]);
    }
}

// ---------------------------------------------------------------------------
// k_mlp2: fused 2-layer MLP via MFMA, 64 rows/block, 4 waves.
//   layer1: K=7(6) padded to 32, one mfma per 16x16 N-tile (16 tiles)
//   layer2: M=64 N=128 K=256, wave w owns M-tile w, 8 nt x 8 ks mfma
// Writes e transposed [col 0..127][row] as bf16.
// ---------------------------------------------------------------------------
template<int NPB, int NODE0, int INOFF, int INDIM>
__global__ __launch_bounds__(256, 4) void k_mlp2(
    const float* __restrict__ state,
    const unsigned short* __restrict__ W0b, const float* __restrict__ b0,
    const unsigned short* __restrict__ W1f, const float* __restrict__ b1,
    unsigned short* __restrict__ eT, int NR)
{
    // LDS: [Xs fp32 64x9 | hs bf16 64x264]  aliased with  [es bf16 128x72]
    __shared__ __align__(16) char smem[2304 + 64 * 264 * 2];
    float* Xs = (float*)smem;                              // [64][9]
    unsigned short* hs = (unsigned short*)(smem + 2304);   // [64][264]
    unsigned short* es = (unsigned short*)smem;            // [128][72]

    const int t = threadIdx.x;
    const int lane = t & 63;
    const int w = t >> 6;
    const int l15 = lane & 15;
    const int quad = lane >> 4;
    const int row0 = blockIdx.x * 64;

    // stage X rows [64][j<8] as fp32
    for (int idx = t; idx < 512; idx += 256) {
        int r = idx & 63, j = idx >> 6;
        float v = 0.f;
        if (j < INDIM) {
            int row = row0 + r;
            int b = row / NPB;
            int n = row - b * NPB + NODE0;
            v = state[((size_t)b * NSTATE + n) * DIN + INOFF + j];
        }
        Xs[r * 9 + j] = v;
    }
    __syncthreads();

    // ---- layer 1: h = relu(X @ W0 + b0), wave w -> rows w*16..w*16+15 ----
    {
        bf16x8 a = {};
        if (quad == 0) {
            #pragma unroll
            for (int j = 0; j < INDIM; ++j)
                a[j] = (short)f2b(Xs[(w * 16 + l15) * 9 + j]);
        }
        #pragma unroll
        for (int nt = 0; nt < 16; ++nt) {
            bf16x8 bf = {};
            if (quad == 0)
                bf = *(const bf16x8*)(W0b + (nt * 16 + l15) * 8);
            float bias = b0[nt * 16 + l15];
            f32x4 c = {bias, bias, bias, bias};
            c = __builtin_amdgcn_mfma_f32_16x16x32_bf16(a, bf, c, 0, 0, 0);
            #pragma unroll
            for (int reg = 0; reg < 4; ++reg)
                hs[(w * 16 + quad * 4 + reg) * 264 + nt * 16 + l15] = f2b(fmaxf(c[reg], 0.f));
        }
    }
    __syncthreads();

    // ---- layer 2: e = relu(h @ W1 + b1) ----
    f32x4 acc[8];
    #pragma unroll
    for (int nt = 0; nt < 8; ++nt) {
        float bias = b1[nt * 16 + l15];
        acc[nt] = (f32x4){bias, bias, bias, bias};
    }
    #pragma unroll
    for (int ks = 0; ks < 8; ++ks) {
        bf16x8 a = *(const bf16x8*)(hs + (w * 16 + l15) * 264 + ks * 32 + quad * 8);
        #pragma unroll
        for (int nt = 0; nt < 8; ++nt) {
            bf16x8 bf = *(const bf16x8*)(W1f + ((ks * 8 + nt) * 64 + lane) * 8);
            acc[nt] = __builtin_amdgcn_mfma_f32_16x16x32_bf16(a, bf, acc[nt], 0, 0, 0);
        }
    }
    __syncthreads();   // all hs reads done before es overwrites the same LDS

    #pragma unroll
    for (int nt = 0; nt < 8; ++nt)
        #pragma unroll
        for (int reg = 0; reg < 4; ++reg)
            es[(nt * 16 + l15) * 72 + w * 16 + quad * 4 + reg] = f2b(fmaxf(acc[nt][reg], 0.f));
    __syncthreads();

    { // coalesced global write: 64B per thread
        int c = t & 127, half = t >> 7;
        const uint4* src = (const uint4*)(es + c * 72 + half * 32);
        uint4 v0 = src[0], v1 = src[1], v2 = src[2], v3 = src[3];
        uint4* dst = (uint4*)(eT + (size_t)c * NR + row0 + half * 32);
        dst[0] = v0; dst[1] = v1; dst[2] = v2; dst[3] = v3;
    }
}

// ---------------------------------------------------------------------------
// k_red: sh[b] = sum_n eh[b,n], so[b] = sum_n eo[b,n]  (feature-major out)
// ---------------------------------------------------------------------------
__global__ __launch_bounds__(256) void k_red(const __hip_bfloat16* __restrict__ eTh,
                                             const __hip_bfloat16* __restrict__ eTo,
                                             float* __restrict__ shT, float* __restrict__ soT)
{
    int gid = blockIdx.x * 256 + threadIdx.x;
    int b = gid & (BATCH - 1);
    int c = gid >> 13;
    const __hip_bfloat16* ph = eTh + (size_t)c * (BATCH * 20) + b * 20;
    float s = 0.f;
    #pragma unroll
    for (int n = 0; n < 20; ++n) s += bf2f(ph[n]);
    shT[(size_t)c * BATCH + b] = s;
    const __hip_bfloat16* po = eTo + (size_t)c * (BATCH * 10) + b * 10;
    float s2 = 0.f;
    #pragma unroll
    for (int n = 0; n < 10; ++n) s2 += bf2f(po[n]);
    soT[(size_t)c * BATCH + b] = s2;
}

// ---------------------------------------------------------------------------
// k_u: [pre_r|ch|co](96) = U(384) @ Wcat + bcat ; xr = relu(pre_r)
// ---------------------------------------------------------------------------
__global__ __launch_bounds__(128) void k_u(
    const __hip_bfloat16* __restrict__ eTr,
    const float* __restrict__ shT, const float* __restrict__ soT,
    const float* __restrict__ Wcat, const float* __restrict__ bcat,
    float* __restrict__ xrT, float* __restrict__ chT, float* __restrict__ coT)
{
    __shared__ float U[384][36];
    const int t = threadIdx.x;
    const int b0 = blockIdx.x * 32;
    for (int idx = t; idx < 384 * 32; idx += 128) {
        int k = idx >> 5, bl = idx & 31;
        float v;
        if (k < 128)      v = bf2f(eTr[(size_t)k * BATCH + b0 + bl]);
        else if (k < 256) v = shT[(size_t)(k - 128) * BATCH + b0 + bl];
        else              v = soT[(size_t)(k - 256) * BATCH + b0 + bl];
        U[k][bl] = v;
    }
    __syncthreads();
    if (t < 96) {
        float acc[32];
        #pragma unroll
        for (int i = 0; i < 32; ++i) acc[i] = 0.f;
        for (int k = 0; k < 384; ++k) {
            float w = Wcat[k * 96 + t];
            #pragma unroll
            for (int i = 0; i < 32; i += 4) {
                float4 u = *(const float4*)&U[k][i];
                acc[i]   = fmaf(u.x, w, acc[i]);
                acc[i+1] = fmaf(u.y, w, acc[i+1]);
                acc[i+2] = fmaf(u.z, w, acc[i+2]);
                acc[i+3] = fmaf(u.w, w, acc[i+3]);
            }
        }
        float bias = bcat[t];
        if (t < 32) {
            float* dst = xrT + (size_t)t * BATCH + b0;
            #pragma unroll
            for (int i = 0; i < 32; ++i) dst[i] = fmaxf(acc[i] + bias, 0.f);
        } else if (t < 64) {
            float* dst = chT + (size_t)(t - 32) * BATCH + b0;
            #pragma unroll
            for (int i = 0; i < 32; ++i) dst[i] = acc[i] + bias;
        } else {
            float* dst = coT + (size_t)(t - 64) * BATCH + b0;
            #pragma unroll
            for (int i = 0; i < 32; ++i) dst[i] = acc[i] + bias;
        }
    }
}

// ---------------------------------------------------------------------------
// k_t: s2[b][m] = sum_n relu(cT[b][m] + e[b,n] @ M[:,m]); 160 rows/block
// ---------------------------------------------------------------------------
template<int NPB>
__global__ __launch_bounds__(256) void k_t(
    const __hip_bfloat16* __restrict__ eT, int NR,
    const float* __restrict__ M, const float* __restrict__ cT,
    float* __restrict__ s2T)
{
    __shared__ float Ml[128][32];
    __shared__ float el[32][164];
    __shared__ float s2l[16][33];
    const int t = threadIdx.x;
    const int m = t & 31, rg = t >> 5;
    const int row0 = blockIdx.x * 160;
    for (int idx = t; idx < 4096; idx += 256) Ml[idx >> 5][idx & 31] = M[idx];
    float acc[20];
    #pragma unroll
    for (int i = 0; i < 20; ++i) acc[i] = 0.f;
    for (int kc = 0; kc < 128; kc += 32) {
        __syncthreads();
        for (int idx = t; idx < 32 * 160; idx += 256) {
            int kk = idx / 160;
            int r = idx - kk * 160;
            el[kk][r] = bf2f(eT[(size_t)(kc + kk) * NR + row0 + r]);
        }
        __syncthreads();
        #pragma unroll 4
        for (int kk = 0; kk < 32; ++kk) {
            float mh = Ml[kc + kk][m];
            const float* ep = &el[kk][rg * 20];
            #pragma unroll
            for (int q = 0; q < 5; ++q) {
                float4 e4 = *(const float4*)(ep + q * 4);
                acc[q*4]   = fmaf(e4.x, mh, acc[q*4]);
                acc[q*4+1] = fmaf(e4.y, mh, acc[q*4+1]);
                acc[q*4+2] = fmaf(e4.z, mh, acc[q*4+2]);
                acc[q*4+3] = fmaf(e4.w, mh, acc[q*4+3]);
            }
        }
    }
    constexpr int BS = 160 / NPB;
    constexpr int BPRG = 20 / NPB;
    #pragma unroll
    for (int bb = 0; bb < BPRG; ++bb) {
        int bl = rg * BPRG + bb;
        int b = blockIdx.x * BS + bl;
        float chv = cT[(size_t)m * BATCH + b];
        float s = 0.f;
        #pragma unroll
        for (int i = 0; i < NPB; ++i) s += fmaxf(chv + acc[bb * NPB + i], 0.f);
        s2l[bl][m] = s;
    }
    __syncthreads();
    for (int idx = t; idx < 32 * BS; idx += 256) {
        int mm = idx / BS, bl = idx - mm * BS;
        s2T[(size_t)mm * BATCH + blockIdx.x * BS + bl] = s2l[bl][mm];
    }
}

// ---------------------------------------------------------------------------
// k_c2: hr = relu(V(96) @ Wc2 + bc2), 32 b per block
// ---------------------------------------------------------------------------
__global__ __launch_bounds__(256) void k_c2(
    const float* __restrict__ xrT, const float* __restrict__ sh2T, const float* __restrict__ so2T,
    const float* __restrict__ Wc2, const float* __restrict__ bc2,
    float* __restrict__ hrT)
{
    __shared__ float V[96][36];
    const int t = threadIdx.x;
    const int b0 = blockIdx.x * 32;
    for (int idx = t; idx < 96 * 32; idx += 256) {
        int k = idx >> 5, bl = idx & 31;
        float v;
        if (k < 32)      v = xrT[(size_t)k * BATCH + b0 + bl];
        else if (k < 64) v = sh2T[(size_t)(k - 32) * BATCH + b0 + bl];
        else             v = so2T[(size_t)(k - 64) * BATCH + b0 + bl];
        V[k][bl] = v;
    }
    __syncthreads();
    const int n = t & 127, bg = t >> 7;
    float acc[16];
    #pragma unroll
    for (int i = 0; i < 16; ++i) acc[i] = 0.f;
    for (int k = 0; k < 96; ++k) {
        float w = Wc2[k * 128 + n];
        #pragma unroll
        for (int i = 0; i < 16; i += 4) {
            float4 u = *(const float4*)&V[k][bg * 16 + i];
            acc[i]   = fmaf(u.x, w, acc[i]);
            acc[i+1] = fmaf(u.y, w, acc[i+1]);
            acc[i+2] = fmaf(u.z, w, acc[i+2]);
            acc[i+3] = fmaf(u.w, w, acc[i+3]);
        }
    }
    float bias = bc2[n];
    float* dst = hrT + (size_t)n * BATCH + b0 + bg * 16;
    #pragma unroll
    for (int i = 0; i < 16; ++i) dst[i] = fmaxf(acc[i] + bias, 0.f);
}

// ---------------------------------------------------------------------------
// k_v1: v1 = relu(hr(128) @ vW0 + vb0) -> 256 cols, 32 b per block
// ---------------------------------------------------------------------------
__global__ __launch_bounds__(256) void k_v1(
    const float* __restrict__ hrT, const float* __restrict__ W, const float* __restrict__ bias_,
    float* __restrict__ v1T)
{
    __shared__ float A[128][36];
    const int t = threadIdx.x;
    const int b0 = blockIdx.x * 32;
    for (int idx = t; idx < 128 * 32; idx += 256) {
        int k = idx >> 5, bl = idx & 31;
        A[k][bl] = hrT[(size_t)k * BATCH + b0 + bl];
    }
    __syncthreads();
    float acc[32];
    #pragma unroll
    for (int i = 0; i < 32; ++i) acc[i] = 0.f;
    for (int k = 0; k < 128; ++k) {
        float w = W[k * 256 + t];
        #pragma unroll
        for (int i = 0; i < 32; i += 4) {
            float4 u = *(const float4*)&A[k][i];
            acc[i]   = fmaf(u.x, w, acc[i]);
            acc[i+1] = fmaf(u.y, w, acc[i+1]);
            acc[i+2] = fmaf(u.z, w, acc[i+2]);
            acc[i+3] = fmaf(u.w, w, acc[i+3]);
        }
    }
    float bv = bias_[t];
    float* dst = v1T + (size_t)t * BATCH + b0;
    #pragma unroll
    for (int i = 0; i < 32; ++i) dst[i] = fmaxf(acc[i] + bv, 0.f);
}

// ---------------------------------------------------------------------------
// k_v2: v2 = relu(v1(256) @ vW1 + vb1) -> 128 cols, 32 b per block
// ---------------------------------------------------------------------------
__global__ __launch_bounds__(256) void k_v2(
    const float* __restrict__ v1T, const float* __restrict__ W, const float* __restrict__ bias_,
    float* __restrict__ v2T)
{
    __shared__ float A[256][36];
    const int t = threadIdx.x;
    const int b0 = blockIdx.x * 32;
    for (int idx = t; idx < 256 * 32; idx += 256) {
        int k = idx >> 5, bl = idx & 31;
        A[k][bl] = v1T[(size_t)k * BATCH + b0 + bl];
    }
    __syncthreads();
    const int n = t & 127, bg = t >> 7;
    float acc[16];
    #pragma unroll
    for (int i = 0; i < 16; ++i) acc[i] = 0.f;
    for (int k = 0; k < 256; ++k) {
        float w = W[k * 128 + n];
        #pragma unroll
        for (int i = 0; i < 16; i += 4) {
            float4 u = *(const float4*)&A[k][bg * 16 + i];
            acc[i]   = fmaf(u.x, w, acc[i]);
            acc[i+1] = fmaf(u.y, w, acc[i+1]);
            acc[i+2] = fmaf(u.z, w, acc[i+2]);
            acc[i+3] = fmaf(u.w, w, acc[i+3]);
        }
    }
    float bv = bias_[n];
    float* dst = v2T + (size_t)n * BATCH + b0 + bg * 16;
    #pragma unroll
    for (int i = 0; i < 16; ++i) dst[i] = fmaxf(acc[i] + bv, 0.f);
}

// ---------------------------------------------------------------------------
// k_v3: out[b] = v2[b] . vW2 + vb2
// ---------------------------------------------------------------------------
__global__ __launch_bounds__(256) void k_v3(
    const float* __restrict__ v2T, const float* __restrict__ W2, const float* __restrict__ b2,
    float* __restrict__ out)
{
    int b = blockIdx.x * 256 + threadIdx.x;
    float acc = b2[0];
    for (int k = 0; k < 128; ++k)
        acc = fmaf(v2T[(size_t)k * BATCH + b], W2[k], acc);
    out[b] = acc;
}

// ---------------------------------------------------------------------------
extern "C" void kernel_launch(void* const* d_in, const int* in_sizes, int n_in,
                              void* d_out, int out_size, void* d_ws, size_t ws_size,
                              hipStream_t stream)
{
    const float* state   = (const float*)d_in[0];
    const float* wr_W0   = (const float*)d_in[2];
    const float* wr_b0   = (const float*)d_in[3];
    const float* wr_W1   = (const float*)d_in[4];
    const float* wr_b1   = (const float*)d_in[5];
    const float* wh_W0   = (const float*)d_in[6];
    const float* wh_b0   = (const float*)d_in[7];
    const float* wh_W1   = (const float*)d_in[8];
    const float* wh_b1   = (const float*)d_in[9];
    const float* wo_W0   = (const float*)d_in[10];
    const float* wo_b0   = (const float*)d_in[11];
    const float* wo_W1   = (const float*)d_in[12];
    const float* wo_b1   = (const float*)d_in[13];
    const float* c1_relW = (const float*)d_in[14];
    const float* c1_relb = (const float*)d_in[15];
    const float* c1_rootW= (const float*)d_in[16];
    const float* c2_relW = (const float*)d_in[17];
    const float* c2_relb = (const float*)d_in[18];
    const float* c2_rootW= (const float*)d_in[19];
    const float* v_W0    = (const float*)d_in[20];
    const float* v_b0    = (const float*)d_in[21];
    const float* v_W1    = (const float*)d_in[22];
    const float* v_b1    = (const float*)d_in[23];
    const float* v_W2    = (const float*)d_in[24];
    const float* v_b2    = (const float*)d_in[25];

    char* ws = (char*)d_ws;
    size_t off = 0;
    auto alloc = [&](size_t bytes) -> char* {
        char* p = ws + off;
        off = (off + bytes + 255) & ~(size_t)255;
        return p;
    };
    unsigned short* eTh = (unsigned short*)alloc((size_t)128 * 163840 * 2);
    unsigned short* eTo = (unsigned short*)alloc((size_t)128 * 81920 * 2);
    unsigned short* eTr = (unsigned short*)alloc((size_t)128 * 8192 * 2);
    float* shT  = (float*)alloc((size_t)128 * 8192 * 4);
    float* soT  = (float*)alloc((size_t)128 * 8192 * 4);
    float* xrT  = (float*)alloc((size_t)32 * 8192 * 4);
    float* chT  = (float*)alloc((size_t)32 * 8192 * 4);
    float* coT  = (float*)alloc((size_t)32 * 8192 * 4);
    float* sh2T = (float*)alloc((size_t)32 * 8192 * 4);
    float* so2T = (float*)alloc((size_t)32 * 8192 * 4);
    float* hrT  = (float*)alloc((size_t)128 * 8192 * 4);
    float* v1T  = (float*)alloc((size_t)256 * 8192 * 4);
    float* v2T  = (float*)alloc((size_t)128 * 8192 * 4);
    float* Mh   = (float*)alloc(4096 * 4);
    float* Mo   = (float*)alloc(4096 * 4);
    float* Wcat = (float*)alloc(36864 * 4);
    float* bcat = (float*)alloc(96 * 4);
    float* Wc2  = (float*)alloc(12288 * 4);
    float* bc2  = (float*)alloc(128 * 4);
    unsigned short* W0b_h = (unsigned short*)alloc(2048 * 2);
    unsigned short* W0b_o = (unsigned short*)alloc(2048 * 2);
    unsigned short* W0b_r = (unsigned short*)alloc(2048 * 2);
    unsigned short* W1f_h = (unsigned short*)alloc(32768 * 2);
    unsigned short* W1f_o = (unsigned short*)alloc(32768 * 2);
    unsigned short* W1f_r = (unsigned short*)alloc(32768 * 2);
    (void)ws_size; (void)in_sizes; (void)n_in; (void)out_size;

    k_prep<<<64, 256, 0, stream>>>(c1_relW, c1_relb, c1_rootW, c2_relW, c2_relb, c2_rootW,
                                   wh_W0, wh_W1, wo_W0, wo_W1, wr_W0, wr_W1,
                                   Mh, Mo, Wcat, bcat, Wc2, bc2,
                                   W0b_h, W0b_o, W0b_r, W1f_h, W1f_o, W1f_r);
    k_mlp2<20, 0, 6, 7><<<2560, 256, 0, stream>>>(state, W0b_h, wh_b0, W1f_h, wh_b1, eTh, 163840);
    k_mlp2<10, 20, 6, 7><<<1280, 256, 0, stream>>>(state, W0b_o, wo_b0, W1f_o, wo_b1, eTo, 81920);
    k_mlp2<1, 0, 0, 6><<<128, 256, 0, stream>>>(state, W0b_r, wr_b0, W1f_r, wr_b1, eTr, 8192);
    k_red<<<4096, 256, 0, stream>>>((const __hip_bfloat16*)eTh, (const __hip_bfloat16*)eTo, shT, soT);
    k_u<<<256, 128, 0, stream>>>((const __hip_bfloat16*)eTr, shT, soT, Wcat, bcat, xrT, chT, coT);
    k_t<20><<<1024, 256, 0, stream>>>((const __hip_bfloat16*)eTh, 163840, Mh, chT, sh2T);
    k_t<10><<<512, 256, 0, stream>>>((const __hip_bfloat16*)eTo, 81920, Mo, coT, so2T);
    k_c2<<<256, 256, 0, stream>>>(xrT, sh2T, so2T, Wc2, bc2, hrT);
    k_v1<<<256, 256, 0, stream>>>(hrT, v_W0, v_b0, v1T);
    k_v2<<<256, 256, 0, stream>>>(v1T, v_W1, v_b1, v2T);
    k_v3<<<32, 256, 0, stream>>>(v2T, v_W2, v_b2, (float*)d_out);
}

// Round 5
// 334.007 us; speedup vs baseline: 1.8081x; 1.2792x over previous
//
#include <hip/hip_runtime.h>
#include <hip/hip_bf16.h>
#include <stdint.h>

#define BATCH 8192
#define NSTATE 30
#define DIN 13
#define E1 256
#define E2 128

typedef short bf16x8 __attribute__((ext_vector_type(8)));
typedef float f32x4 __attribute__((ext_vector_type(4)));

// f32 -> bf16 bits, round-to-nearest-even
__device__ __forceinline__ unsigned short f2b(float f) {
    unsigned u = __float_as_uint(f);
    u += 0x7FFFu + ((u >> 16) & 1u);
    return (unsigned short)(u >> 16);
}
__device__ __forceinline__ float b2f(unsigned short b) {
    return __uint_as_float((unsigned)b << 16);
}

// combined conv1 weight values (derived in R1, verified)
__device__ __forceinline__ float wcat_val(int k, int m, const float* relW, const float* rootW) {
    int part = k >> 7, c = k & 127, grp = m >> 5, mm = m & 31;
    int off = c * 32 + mm;
    if (part == 0) return (grp == 0) ? rootW[4096 + off] + rootW[8192 + off]
                        : (grp == 1) ? relW[off] : relW[3*4096 + off];
    if (part == 1) return (grp == 0) ? relW[1*4096 + off]
                        : (grp == 1) ? relW[6*4096 + off] : relW[5*4096 + off];
    return (grp == 0) ? relW[2*4096 + off]
         : (grp == 1) ? relW[4*4096 + off] : relW[7*4096 + off];
}
__device__ __forceinline__ float wc2_val(int k, int n, const float* relW, const float* rootW) {
    int grp = k >> 5, kk = k & 31;
    int off = kk * 128 + n;
    if (grp == 0) return rootW[4096 + off] + rootW[8192 + off];
    if (grp == 1) return relW[4096 + off];
    return relW[8192 + off];
}

// ---------------------------------------------------------------------------
// k_prep: bias vectors + ALL bf16 MFMA fragment tables.
// Fragment decode (verified via W1f in R3): entry i -> j=i&7, l=(i>>3)&63,
//   k = ks*32 + (l>>4)*8 + j,  n = nt*16 + (l&15),  table [(ks*NT+nt)*64+l][8]
// ---------------------------------------------------------------------------
__global__ void k_prep(const float* __restrict__ c1_relW, const float* __restrict__ c1_relb,
                       const float* __restrict__ c1_rootW,
                       const float* __restrict__ c2_relW, const float* __restrict__ c2_relb,
                       const float* __restrict__ c2_rootW,
                       const float* __restrict__ wh_W0, const float* __restrict__ wh_W1,
                       const float* __restrict__ wo_W0, const float* __restrict__ wo_W1,
                       const float* __restrict__ wr_W0, const float* __restrict__ wr_W1,
                       const float* __restrict__ v_W0, const float* __restrict__ v_W1,
                       float* __restrict__ bcat, float* __restrict__ bc2,
                       unsigned short* __restrict__ W0b_h, unsigned short* __restrict__ W0b_o,
                       unsigned short* __restrict__ W0b_r,
                       unsigned short* __restrict__ W1f_h, unsigned short* __restrict__ W1f_o,
                       unsigned short* __restrict__ W1f_r,
                       unsigned short* __restrict__ Mf_h, unsigned short* __restrict__ Mf_o,
                       unsigned short* __restrict__ Wcatf, unsigned short* __restrict__ Wc2f,
                       unsigned short* __restrict__ vW0f, unsigned short* __restrict__ vW1f)
{
    int gid = blockIdx.x * blockDim.x + threadIdx.x;
    int gsz = gridDim.x * blockDim.x;

    for (int i = gid; i < 96; i += gsz) {
        int grp = i >> 5, mm = i & 31;
        float v;
        if (grp == 0)      v = c1_relb[32 + mm] + c1_relb[64 + mm];
        else if (grp == 1) v = c1_relb[mm] + c1_relb[128 + mm] + c1_relb[192 + mm];
        else               v = c1_relb[96 + mm] + c1_relb[160 + mm] + c1_relb[224 + mm];
        bcat[i] = v;
    }
    for (int i = gid; i < 128; i += gsz) bc2[i] = c2_relb[128 + i] + c2_relb[256 + i];

    // layer-1 weights, fragment-padded to k=8
    for (int i = gid; i < 2048; i += gsz) {
        int n = i >> 3, j = i & 7;
        W0b_h[i] = (j < 7) ? f2b(wh_W0[j * 256 + n]) : 0;
        W0b_o[i] = (j < 7) ? f2b(wo_W0[j * 256 + n]) : 0;
        W0b_r[i] = (j < 6) ? f2b(wr_W0[j * 256 + n]) : 0;
    }
    // layer-2 weights: 8 ks x 8 nt (K=256, N=128) -> 32768
    for (int i = gid; i < 32768; i += gsz) {
        int j = i & 7, l = (i >> 3) & 63, nt = (i >> 9) & 7, ks = i >> 12;
        int k = ks * 32 + (l >> 4) * 8 + j;
        int n = nt * 16 + (l & 15);
        W1f_h[i] = f2b(wh_W1[k * 128 + n]);
        W1f_o[i] = f2b(wo_W1[k * 128 + n]);
        W1f_r[i] = f2b(wr_W1[k * 128 + n]);
    }
    // Mh/Mo: 4 ks x 2 nt (K=128, N=32) -> 4096
    for (int i = gid; i < 4096; i += gsz) {
        int j = i & 7, l = (i >> 3) & 63, nt = (i >> 9) & 1, ks = i >> 10;
        int k = ks * 32 + (l >> 4) * 8 + j;
        int n = nt * 16 + (l & 15);
        int i0 = k * 32 + n;
        Mf_h[i] = f2b(c1_rootW[i0] + c1_rootW[4*4096 + i0] + c1_rootW[6*4096 + i0] - c1_relW[6*4096 + i0]);
        Mf_o[i] = f2b(c1_rootW[3*4096 + i0] + c1_rootW[5*4096 + i0] + c1_rootW[7*4096 + i0] - c1_relW[7*4096 + i0]);
    }
    // Wcat: 12 ks x 6 nt (K=384, N=96) -> 36864
    for (int i = gid; i < 36864; i += gsz) {
        int j = i & 7, l = (i >> 3) & 63, rem = i >> 9;
        int nt = rem % 6, ks = rem / 6;
        int k = ks * 32 + (l >> 4) * 8 + j;
        int n = nt * 16 + (l & 15);
        Wcatf[i] = f2b(wcat_val(k, n, c1_relW, c1_rootW));
    }
    // Wc2: 3 ks x 8 nt (K=96, N=128) -> 12288
    for (int i = gid; i < 12288; i += gsz) {
        int j = i & 7, l = (i >> 3) & 63, rem = i >> 9;
        int nt = rem & 7, ks = rem >> 3;
        int k = ks * 32 + (l >> 4) * 8 + j;
        int n = nt * 16 + (l & 15);
        Wc2f[i] = f2b(wc2_val(k, n, c2_relW, c2_rootW));
    }
    // vW0: 4 ks x 16 nt (K=128, N=256) -> 32768
    for (int i = gid; i < 32768; i += gsz) {
        int j = i & 7, l = (i >> 3) & 63, rem = i >> 9;
        int nt = rem & 15, ks = rem >> 4;
        int k = ks * 32 + (l >> 4) * 8 + j;
        int n = nt * 16 + (l & 15);
        vW0f[i] = f2b(v_W0[k * 256 + n]);
    }
    // vW1: 8 ks x 8 nt (K=256, N=128) -> 32768
    for (int i = gid; i < 32768; i += gsz) {
        int j = i & 7, l = (i >> 3) & 63, rem = i >> 9;
        int nt = rem & 7, ks = rem >> 3;
        int k = ks * 32 + (l >> 4) * 8 + j;
        int n = nt * 16 + (l & 15);
        vW1f[i] = f2b(v_W1[k * 128 + n]);
    }
}

// ---------------------------------------------------------------------------
// k_mlp3: fused 2-layer MLP via MFMA, 64 rows/block, 4 waves.
// TAIL=true:  epilogue computes t = e@M -> tT (bf16, feature-major) and
//             atomically accumulates sh/so (fp32) per (col, b). No eT write.
// TAIL=false: (root) writes eT [128][NR] bf16 feature-major (R3-verified path,
//             FULL 4x uint4 per (c,half) -- R4 bug was writing only 2).
// ---------------------------------------------------------------------------
template<int NPB, int NODE0, int INOFF, int INDIM, bool TAIL>
__global__ __launch_bounds__(256, 4) void k_mlp3(
    const float* __restrict__ state,
    const unsigned short* __restrict__ W0b, const float* __restrict__ b0,
    const unsigned short* __restrict__ W1f, const float* __restrict__ b1,
    const unsigned short* __restrict__ Mf,
    unsigned short* __restrict__ tT,
    float* __restrict__ sumT,
    unsigned short* __restrict__ eT,
    int NR)
{
    __shared__ __align__(16) char smem[2304 + 64 * 264 * 2];
    float* Xs = (float*)smem;                              // [64][9]
    unsigned short* hs = (unsigned short*)(smem + 2304);   // [64][264]
    unsigned short* esA = (unsigned short*)smem;           // TAIL: [64 rows][136 cols]
    unsigned short* esB = (unsigned short*)smem;           // !TAIL: [128 cols][72 rows]

    const int t = threadIdx.x;
    const int lane = t & 63;
    const int w = t >> 6;
    const int l15 = lane & 15;
    const int quad = lane >> 4;
    const int row0 = blockIdx.x * 64;

    for (int idx = t; idx < 512; idx += 256) {
        int r = idx & 63, j = idx >> 6;
        float v = 0.f;
        if (j < INDIM) {
            int row = row0 + r;
            int b = row / NPB;
            int n = row - b * NPB + NODE0;
            v = state[((size_t)b * NSTATE + n) * DIN + INOFF + j];
        }
        Xs[r * 9 + j] = v;
    }
    __syncthreads();

    // ---- layer 1 ----
    {
        bf16x8 a = {};
        if (quad == 0) {
            #pragma unroll
            for (int j = 0; j < INDIM; ++j)
                a[j] = (short)f2b(Xs[(w * 16 + l15) * 9 + j]);
        }
        #pragma unroll
        for (int nt = 0; nt < 16; ++nt) {
            bf16x8 bf = {};
            if (quad == 0)
                bf = *(const bf16x8*)(W0b + (nt * 16 + l15) * 8);
            float bias = b0[nt * 16 + l15];
            f32x4 c = {bias, bias, bias, bias};
            c = __builtin_amdgcn_mfma_f32_16x16x32_bf16(a, bf, c, 0, 0, 0);
            #pragma unroll
            for (int reg = 0; reg < 4; ++reg)
                hs[(w * 16 + quad * 4 + reg) * 264 + nt * 16 + l15] = f2b(fmaxf(c[reg], 0.f));
        }
    }
    __syncthreads();

    // ---- layer 2 ----
    f32x4 acc[8];
    #pragma unroll
    for (int nt = 0; nt < 8; ++nt) {
        float bias = b1[nt * 16 + l15];
        acc[nt] = (f32x4){bias, bias, bias, bias};
    }
    #pragma unroll
    for (int ks = 0; ks < 8; ++ks) {
        bf16x8 a = *(const bf16x8*)(hs + (w * 16 + l15) * 264 + ks * 32 + quad * 8);
        #pragma unroll
        for (int nt = 0; nt < 8; ++nt) {
            bf16x8 bf = *(const bf16x8*)(W1f + ((ks * 8 + nt) * 64 + lane) * 8);
            acc[nt] = __builtin_amdgcn_mfma_f32_16x16x32_bf16(a, bf, acc[nt], 0, 0, 0);
        }
    }
    __syncthreads();   // hs reads done before es overwrites same LDS

    if constexpr (TAIL) {
        // e -> LDS row-major [64][136]
        #pragma unroll
        for (int nt = 0; nt < 8; ++nt)
            #pragma unroll
            for (int reg = 0; reg < 4; ++reg)
                esA[(w * 16 + quad * 4 + reg) * 136 + nt * 16 + l15] = f2b(fmaxf(acc[nt][reg], 0.f));
        __syncthreads();

        // t = e @ M  (K=128, N=32), wave w -> rows w*16..+15
        f32x4 tacc[2] = {{0.f,0.f,0.f,0.f},{0.f,0.f,0.f,0.f}};
        #pragma unroll
        for (int ks = 0; ks < 4; ++ks) {
            bf16x8 a = *(const bf16x8*)(esA + (w * 16 + l15) * 136 + ks * 32 + quad * 8);
            #pragma unroll
            for (int nt = 0; nt < 2; ++nt) {
                bf16x8 bm = *(const bf16x8*)(Mf + ((ks * 2 + nt) * 64 + lane) * 8);
                tacc[nt] = __builtin_amdgcn_mfma_f32_16x16x32_bf16(a, bm, tacc[nt], 0, 0, 0);
            }
        }
        #pragma unroll
        for (int nt = 0; nt < 2; ++nt)
            #pragma unroll
            for (int reg = 0; reg < 4; ++reg)
                tT[(size_t)(nt * 16 + l15) * NR + row0 + w * 16 + quad * 4 + reg] = f2b(tacc[nt][reg]);

        // sh/so: col-wise sums bucketed by b, fp32 atomics
        if (t < 128) {
            float s = 0.f;
            int bcur = row0 / NPB;
            for (int r = 0; r < 64; ++r) {
                int b = (row0 + r) / NPB;
                if (b != bcur) {
                    atomicAdd(&sumT[(size_t)t * BATCH + bcur], s);
                    s = 0.f; bcur = b;
                }
                s += b2f(esA[r * 136 + t]);
            }
            atomicAdd(&sumT[(size_t)t * BATCH + bcur], s);
        }
    } else {
        #pragma unroll
        for (int nt = 0; nt < 8; ++nt)
            #pragma unroll
            for (int reg = 0; reg < 4; ++reg)
                esB[(nt * 16 + l15) * 72 + w * 16 + quad * 4 + reg] = f2b(fmaxf(acc[nt][reg], 0.f));
        __syncthreads();
        int c = t & 127, half = t >> 7;
        const uint4* src = (const uint4*)(esB + c * 72 + half * 32);
        uint4 v0 = src[0], v1 = src[1], v2 = src[2], v3 = src[3];
        uint4* dst = (uint4*)(eT + (size_t)c * NR + row0 + half * 32);
        dst[0] = v0; dst[1] = v1; dst[2] = v2; dst[3] = v3;
    }
}

// ---------------------------------------------------------------------------
// k_u2: [xr|ch|co](96) = U(384) @ Wcat + bcat via MFMA; 32 b/block, 256 blocks.
// ---------------------------------------------------------------------------
__global__ __launch_bounds__(256) void k_u2(
    const unsigned short* __restrict__ eTr,
    const float* __restrict__ shT, const float* __restrict__ soT,
    const unsigned short* __restrict__ Wcatf, const float* __restrict__ bcat,
    unsigned short* __restrict__ xrT, float* __restrict__ chT, float* __restrict__ coT)
{
    __shared__ __align__(16) unsigned short Ub[32 * 400];   // [b][k], pitch 400
    const int t = threadIdx.x, lane = t & 63, w = t >> 6;
    const int l15 = lane & 15, quad = lane >> 4;
    const int b0 = blockIdx.x * 32;

    for (int idx = t; idx < 32 * 384; idx += 256) {
        int k = idx >> 5, b = idx & 31;
        unsigned short v;
        if (k < 128)      v = eTr[(size_t)k * BATCH + b0 + b];
        else if (k < 256) v = f2b(shT[(size_t)(k - 128) * BATCH + b0 + b]);
        else              v = f2b(soT[(size_t)(k - 256) * BATCH + b0 + b]);
        Ub[b * 400 + k] = v;
    }
    __syncthreads();

    const int mt = w >> 1, ntg = (w & 1) * 3;
    f32x4 acc[3];
    #pragma unroll
    for (int q = 0; q < 3; ++q) {
        float bias = bcat[(ntg + q) * 16 + l15];
        acc[q] = (f32x4){bias, bias, bias, bias};
    }
    #pragma unroll
    for (int ks = 0; ks < 12; ++ks) {
        bf16x8 a = *(const bf16x8*)(Ub + (mt * 16 + l15) * 400 + ks * 32 + quad * 8);
        #pragma unroll
        for (int q = 0; q < 3; ++q) {
            bf16x8 bw = *(const bf16x8*)(Wcatf + ((ks * 6 + ntg + q) * 64 + lane) * 8);
            acc[q] = __builtin_amdgcn_mfma_f32_16x16x32_bf16(a, bw, acc[q], 0, 0, 0);
        }
    }
    int brow = b0 + mt * 16 + quad * 4;
    #pragma unroll
    for (int q = 0; q < 3; ++q) {
        int n = (ntg + q) * 16 + l15;
        #pragma unroll
        for (int reg = 0; reg < 4; ++reg) {
            float v = acc[q][reg];
            int b = brow + reg;
            if (n < 32)      xrT[(size_t)n * BATCH + b] = f2b(fmaxf(v, 0.f));
            else if (n < 64) chT[(size_t)(n - 32) * BATCH + b] = v;
            else             coT[(size_t)(n - 64) * BATCH + b] = v;
        }
    }
}

// ---------------------------------------------------------------------------
// k_s: s2[b][m] = sum_n relu(c[b][m] + t[b,n][m])
// ---------------------------------------------------------------------------
template<int NPB>
__global__ __launch_bounds__(256) void k_s(
    const unsigned short* __restrict__ tT, int NR,
    const float* __restrict__ cT,
    unsigned short* __restrict__ s2T)
{
    int gid = blockIdx.x * 256 + threadIdx.x;   // 32 * 8192
    int b = gid & (BATCH - 1), m = gid >> 13;
    const unsigned short* p = tT + (size_t)m * NR + b * NPB;
    float c = cT[(size_t)m * BATCH + b];
    float s = 0.f;
    #pragma unroll
    for (int n = 0; n < NPB; ++n)
        s += fmaxf(c + b2f(p[n]), 0.f);
    s2T[(size_t)m * BATCH + b] = f2b(s);
}

// ---------------------------------------------------------------------------
// k_v: fused c2 + value-MLP via MFMA. 32 b/block, 256 blocks.
//   V(96) -> hr(128) -> v1(256) -> v2(128) -> out(1)
// ---------------------------------------------------------------------------
__global__ __launch_bounds__(256) void k_v(
    const unsigned short* __restrict__ xrT, const unsigned short* __restrict__ s2hT,
    const unsigned short* __restrict__ s2oT,
    const unsigned short* __restrict__ Wc2f, const float* __restrict__ bc2,
    const unsigned short* __restrict__ vW0f, const float* __restrict__ vb0,
    const unsigned short* __restrict__ vW1f, const float* __restrict__ vb1,
    const float* __restrict__ vW2, const float* __restrict__ vb2,
    float* __restrict__ out)
{
    __shared__ __align__(16) unsigned short Vb[32 * 104];
    __shared__ __align__(16) unsigned short Hb[32 * 136];
    __shared__ __align__(16) unsigned short V1b[32 * 264];
    __shared__ __align__(16) float V2b[32 * 132];
    const int t = threadIdx.x, lane = t & 63, w = t >> 6;
    const int l15 = lane & 15, quad = lane >> 4;
    const int b0 = blockIdx.x * 32;
    const int mt = w >> 1, nh = w & 1;
    const int rowb = mt * 16 + quad * 4;

    for (int idx = t; idx < 32 * 96; idx += 256) {
        int k = idx >> 5, b = idx & 31;
        unsigned short v;
        if (k < 32)      v = xrT[(size_t)k * BATCH + b0 + b];
        else if (k < 64) v = s2hT[(size_t)(k - 32) * BATCH + b0 + b];
        else             v = s2oT[(size_t)(k - 64) * BATCH + b0 + b];
        Vb[b * 104 + k] = v;
    }
    __syncthreads();

    { // c2: K=96 (3 ks), N=128, wave handles 4 nt
        const int ntg = nh * 4;
        f32x4 acc[4];
        #pragma unroll
        for (int q = 0; q < 4; ++q) {
            float bias = bc2[(ntg + q) * 16 + l15];
            acc[q] = (f32x4){bias, bias, bias, bias};
        }
        #pragma unroll
        for (int ks = 0; ks < 3; ++ks) {
            bf16x8 a = *(const bf16x8*)(Vb + (mt * 16 + l15) * 104 + ks * 32 + quad * 8);
            #pragma unroll
            for (int q = 0; q < 4; ++q) {
                bf16x8 bw = *(const bf16x8*)(Wc2f + ((ks * 8 + ntg + q) * 64 + lane) * 8);
                acc[q] = __builtin_amdgcn_mfma_f32_16x16x32_bf16(a, bw, acc[q], 0, 0, 0);
            }
        }
        #pragma unroll
        for (int q = 0; q < 4; ++q)
            #pragma unroll
            for (int reg = 0; reg < 4; ++reg)
                Hb[(rowb + reg) * 136 + (ntg + q) * 16 + l15] = f2b(fmaxf(acc[q][reg], 0.f));
    }
    __syncthreads();

    { // v1: K=128 (4 ks), N=256, wave handles 8 nt
        const int ntg = nh * 8;
        f32x4 acc[8];
        #pragma unroll
        for (int q = 0; q < 8; ++q) {
            float bias = vb0[(ntg + q) * 16 + l15];
            acc[q] = (f32x4){bias, bias, bias, bias};
        }
        #pragma unroll
        for (int ks = 0; ks < 4; ++ks) {
            bf16x8 a = *(const bf16x8*)(Hb + (mt * 16 + l15) * 136 + ks * 32 + quad * 8);
            #pragma unroll
            for (int q = 0; q < 8; ++q) {
                bf16x8 bw = *(const bf16x8*)(vW0f + ((ks * 16 + ntg + q) * 64 + lane) * 8);
                acc[q] = __builtin_amdgcn_mfma_f32_16x16x32_bf16(a, bw, acc[q], 0, 0, 0);
            }
        }
        __syncthreads();
        #pragma unroll
        for (int q = 0; q < 8; ++q)
            #pragma unroll
            for (int reg = 0; reg < 4; ++reg)
                V1b[(rowb + reg) * 264 + (ntg + q) * 16 + l15] = f2b(fmaxf(acc[q][reg], 0.f));
    }
    __syncthreads();

    { // v2: K=256 (8 ks), N=128, wave handles 4 nt
        const int ntg = nh * 4;
        f32x4 acc[4];
        #pragma unroll
        for (int q = 0; q < 4; ++q) {
            float bias = vb1[(ntg + q) * 16 + l15];
            acc[q] = (f32x4){bias, bias, bias, bias};
        }
        #pragma unroll
        for (int ks = 0; ks < 8; ++ks) {
            bf16x8 a = *(const bf16x8*)(V1b + (mt * 16 + l15) * 264 + ks * 32 + quad * 8);
            #pragma unroll
            for (int q = 0; q < 4; ++q) {
                bf16x8 bw = *(const bf16x8*)(vW1f + ((ks * 8 + ntg + q) * 64 + lane) * 8);
                acc[q] = __builtin_amdgcn_mfma_f32_16x16x32_bf16(a, bw, acc[q], 0, 0, 0);
            }
        }
        #pragma unroll
        for (int q = 0; q < 4; ++q)
            #pragma unroll
            for (int reg = 0; reg < 4; ++reg)
                V2b[(rowb + reg) * 132 + (ntg + q) * 16 + l15] = fmaxf(acc[q][reg], 0.f);
    }
    __syncthreads();

    if (t < 32) {
        float acc = vb2[0];
        for (int k = 0; k < 128; ++k)
            acc = fmaf(V2b[t * 132 + k], vW2[k], acc);
        out[b0 + t] = acc;
    }
}

// ---------------------------------------------------------------------------
extern "C" void kernel_launch(void* const* d_in, const int* in_sizes, int n_in,
                              void* d_out, int out_size, void* d_ws, size_t ws_size,
                              hipStream_t stream)
{
    const float* state   = (const float*)d_in[0];
    const float* wr_W0   = (const float*)d_in[2];
    const float* wr_b0   = (const float*)d_in[3];
    const float* wr_W1   = (const float*)d_in[4];
    const float* wr_b1   = (const float*)d_in[5];
    const float* wh_W0   = (const float*)d_in[6];
    const float* wh_b0   = (const float*)d_in[7];
    const float* wh_W1   = (const float*)d_in[8];
    const float* wh_b1   = (const float*)d_in[9];
    const float* wo_W0   = (const float*)d_in[10];
    const float* wo_b0   = (const float*)d_in[11];
    const float* wo_W1   = (const float*)d_in[12];
    const float* wo_b1   = (const float*)d_in[13];
    const float* c1_relW = (const float*)d_in[14];
    const float* c1_relb = (const float*)d_in[15];
    const float* c1_rootW= (const float*)d_in[16];
    const float* c2_relW = (const float*)d_in[17];
    const float* c2_relb = (const float*)d_in[18];
    const float* c2_rootW= (const float*)d_in[19];
    const float* v_W0    = (const float*)d_in[20];
    const float* v_b0    = (const float*)d_in[21];
    const float* v_W1    = (const float*)d_in[22];
    const float* v_b1    = (const float*)d_in[23];
    const float* v_W2    = (const float*)d_in[24];
    const float* v_b2    = (const float*)d_in[25];

    char* ws = (char*)d_ws;
    size_t off = 0;
    auto alloc = [&](size_t bytes) -> char* {
        char* p = ws + off;
        off = (off + bytes + 255) & ~(size_t)255;
        return p;
    };
    float* shT  = (float*)alloc((size_t)128 * BATCH * 4);          // fp32 atomic sums
    float* soT  = (float*)alloc((size_t)128 * BATCH * 4);          // contiguous with shT
    unsigned short* tT_h = (unsigned short*)alloc((size_t)32 * 163840 * 2);
    unsigned short* tT_o = (unsigned short*)alloc((size_t)32 * 81920 * 2);
    unsigned short* eTr  = (unsigned short*)alloc((size_t)128 * BATCH * 2);
    unsigned short* xrT  = (unsigned short*)alloc((size_t)32 * BATCH * 2);
    float* chT  = (float*)alloc((size_t)32 * BATCH * 4);
    float* coT  = (float*)alloc((size_t)32 * BATCH * 4);
    unsigned short* s2hT = (unsigned short*)alloc((size_t)32 * BATCH * 2);
    unsigned short* s2oT = (unsigned short*)alloc((size_t)32 * BATCH * 2);
    float* bcat = (float*)alloc(96 * 4);
    float* bc2  = (float*)alloc(128 * 4);
    unsigned short* W0b_h = (unsigned short*)alloc(2048 * 2);
    unsigned short* W0b_o = (unsigned short*)alloc(2048 * 2);
    unsigned short* W0b_r = (unsigned short*)alloc(2048 * 2);
    unsigned short* W1f_h = (unsigned short*)alloc(32768 * 2);
    unsigned short* W1f_o = (unsigned short*)alloc(32768 * 2);
    unsigned short* W1f_r = (unsigned short*)alloc(32768 * 2);
    unsigned short* Mf_h  = (unsigned short*)alloc(4096 * 2);
    unsigned short* Mf_o  = (unsigned short*)alloc(4096 * 2);
    unsigned short* Wcatf = (unsigned short*)alloc(36864 * 2);
    unsigned short* Wc2f  = (unsigned short*)alloc(12288 * 2);
    unsigned short* vW0f  = (unsigned short*)alloc(32768 * 2);
    unsigned short* vW1f  = (unsigned short*)alloc(32768 * 2);
    (void)ws_size; (void)in_sizes; (void)n_in; (void)out_size;

    // zero the atomic accumulators (shT+soT contiguous, 8 MB)
    hipMemsetAsync(shT, 0, (size_t)2 * 128 * BATCH * 4, stream);

    k_prep<<<64, 256, 0, stream>>>(c1_relW, c1_relb, c1_rootW, c2_relW, c2_relb, c2_rootW,
                                   wh_W0, wh_W1, wo_W0, wo_W1, wr_W0, wr_W1, v_W0, v_W1,
                                   bcat, bc2, W0b_h, W0b_o, W0b_r, W1f_h, W1f_o, W1f_r,
                                   Mf_h, Mf_o, Wcatf, Wc2f, vW0f, vW1f);

    k_mlp3<20, 0, 6, 7, true><<<2560, 256, 0, stream>>>(state, W0b_h, wh_b0, W1f_h, wh_b1,
                                                        Mf_h, tT_h, shT, nullptr, 163840);
    k_mlp3<10, 20, 6, 7, true><<<1280, 256, 0, stream>>>(state, W0b_o, wo_b0, W1f_o, wo_b1,
                                                         Mf_o, tT_o, soT, nullptr, 81920);
    k_mlp3<1, 0, 0, 6, false><<<128, 256, 0, stream>>>(state, W0b_r, wr_b0, W1f_r, wr_b1,
                                                       nullptr, nullptr, nullptr, eTr, 8192);
    k_u2<<<256, 256, 0, stream>>>(eTr, shT, soT, Wcatf, bcat, xrT, chT, coT);
    k_s<20><<<1024, 256, 0, stream>>>(tT_h, 163840, chT, s2hT);
    k_s<10><<<1024, 256, 0, stream>>>(tT_o, 81920, coT, s2oT);
    k_v<<<256, 256, 0, stream>>>(xrT, s2hT, s2oT, Wc2f, bc2, vW0f, v_b0, vW1f, v_b1,
                                 v_W2, v_b2, (float*)d_out);
}

// Round 6
// 303.237 us; speedup vs baseline: 1.9916x; 1.1015x over previous
//
#include <hip/hip_runtime.h>
#include <hip/hip_bf16.h>
#include <stdint.h>

#define BATCH 8192
#define NSTATE 30
#define DIN 13
#define E1 256
#define E2 128

typedef short bf16x8 __attribute__((ext_vector_type(8)));
typedef float f32x4 __attribute__((ext_vector_type(4)));

// f32 -> bf16 bits, round-to-nearest-even
__device__ __forceinline__ unsigned short f2b(float f) {
    unsigned u = __float_as_uint(f);
    u += 0x7FFFu + ((u >> 16) & 1u);
    return (unsigned short)(u >> 16);
}
__device__ __forceinline__ float b2f(unsigned short b) {
    return __uint_as_float((unsigned)b << 16);
}
// pack two relu'd floats to bf16x2 in a uint
__device__ __forceinline__ unsigned pack2(float a, float b) {
    return ((unsigned)f2b(fmaxf(b, 0.f)) << 16) | f2b(fmaxf(a, 0.f));
}
__device__ __forceinline__ unsigned pack2n(float a, float b) {   // no relu
    return ((unsigned)f2b(b) << 16) | f2b(a);
}

// combined conv1 weight values (derived in R1, verified)
__device__ __forceinline__ float wcat_val(int k, int m, const float* relW, const float* rootW) {
    int part = k >> 7, c = k & 127, grp = m >> 5, mm = m & 31;
    int off = c * 32 + mm;
    if (part == 0) return (grp == 0) ? rootW[4096 + off] + rootW[8192 + off]
                        : (grp == 1) ? relW[off] : relW[3*4096 + off];
    if (part == 1) return (grp == 0) ? relW[1*4096 + off]
                        : (grp == 1) ? relW[6*4096 + off] : relW[5*4096 + off];
    return (grp == 0) ? relW[2*4096 + off]
         : (grp == 1) ? relW[4*4096 + off] : relW[7*4096 + off];
}
__device__ __forceinline__ float wc2_val(int k, int n, const float* relW, const float* rootW) {
    int grp = k >> 5, kk = k & 31;
    int off = kk * 128 + n;
    if (grp == 0) return rootW[4096 + off] + rootW[8192 + off];
    if (grp == 1) return relW[4096 + off];
    return relW[8192 + off];
}

// ---------------------------------------------------------------------------
// k_prep: bias vectors + ALL bf16 MFMA fragment tables (R5-verified decode):
//   entry i -> j=i&7, l=(i>>3)&63, k = ks*32+(l>>4)*8+j, n = nt*16+(l&15)
// ---------------------------------------------------------------------------
__global__ void k_prep(const float* __restrict__ c1_relW, const float* __restrict__ c1_relb,
                       const float* __restrict__ c1_rootW,
                       const float* __restrict__ c2_relW, const float* __restrict__ c2_relb,
                       const float* __restrict__ c2_rootW,
                       const float* __restrict__ wh_W0, const float* __restrict__ wh_W1,
                       const float* __restrict__ wo_W0, const float* __restrict__ wo_W1,
                       const float* __restrict__ wr_W0, const float* __restrict__ wr_W1,
                       const float* __restrict__ v_W0, const float* __restrict__ v_W1,
                       float* __restrict__ bcat, float* __restrict__ bc2,
                       unsigned short* __restrict__ W0b_h, unsigned short* __restrict__ W0b_o,
                       unsigned short* __restrict__ W0b_r,
                       unsigned short* __restrict__ W1f_h, unsigned short* __restrict__ W1f_o,
                       unsigned short* __restrict__ W1f_r,
                       unsigned short* __restrict__ Mf_h, unsigned short* __restrict__ Mf_o,
                       unsigned short* __restrict__ Wcatf, unsigned short* __restrict__ Wc2f,
                       unsigned short* __restrict__ vW0f, unsigned short* __restrict__ vW1f)
{
    int gid = blockIdx.x * blockDim.x + threadIdx.x;
    int gsz = gridDim.x * blockDim.x;

    for (int i = gid; i < 96; i += gsz) {
        int grp = i >> 5, mm = i & 31;
        float v;
        if (grp == 0)      v = c1_relb[32 + mm] + c1_relb[64 + mm];
        else if (grp == 1) v = c1_relb[mm] + c1_relb[128 + mm] + c1_relb[192 + mm];
        else               v = c1_relb[96 + mm] + c1_relb[160 + mm] + c1_relb[224 + mm];
        bcat[i] = v;
    }
    for (int i = gid; i < 128; i += gsz) bc2[i] = c2_relb[128 + i] + c2_relb[256 + i];

    for (int i = gid; i < 2048; i += gsz) {
        int n = i >> 3, j = i & 7;
        W0b_h[i] = (j < 7) ? f2b(wh_W0[j * 256 + n]) : 0;
        W0b_o[i] = (j < 7) ? f2b(wo_W0[j * 256 + n]) : 0;
        W0b_r[i] = (j < 6) ? f2b(wr_W0[j * 256 + n]) : 0;
    }
    for (int i = gid; i < 32768; i += gsz) {
        int j = i & 7, l = (i >> 3) & 63, nt = (i >> 9) & 7, ks = i >> 12;
        int k = ks * 32 + (l >> 4) * 8 + j;
        int n = nt * 16 + (l & 15);
        W1f_h[i] = f2b(wh_W1[k * 128 + n]);
        W1f_o[i] = f2b(wo_W1[k * 128 + n]);
        W1f_r[i] = f2b(wr_W1[k * 128 + n]);
    }
    for (int i = gid; i < 4096; i += gsz) {
        int j = i & 7, l = (i >> 3) & 63, nt = (i >> 9) & 1, ks = i >> 10;
        int k = ks * 32 + (l >> 4) * 8 + j;
        int n = nt * 16 + (l & 15);
        int i0 = k * 32 + n;
        Mf_h[i] = f2b(c1_rootW[i0] + c1_rootW[4*4096 + i0] + c1_rootW[6*4096 + i0] - c1_relW[6*4096 + i0]);
        Mf_o[i] = f2b(c1_rootW[3*4096 + i0] + c1_rootW[5*4096 + i0] + c1_rootW[7*4096 + i0] - c1_relW[7*4096 + i0]);
    }
    for (int i = gid; i < 36864; i += gsz) {
        int j = i & 7, l = (i >> 3) & 63, rem = i >> 9;
        int nt = rem % 6, ks = rem / 6;
        int k = ks * 32 + (l >> 4) * 8 + j;
        int n = nt * 16 + (l & 15);
        Wcatf[i] = f2b(wcat_val(k, n, c1_relW, c1_rootW));
    }
    for (int i = gid; i < 12288; i += gsz) {
        int j = i & 7, l = (i >> 3) & 63, rem = i >> 9;
        int nt = rem & 7, ks = rem >> 3;
        int k = ks * 32 + (l >> 4) * 8 + j;
        int n = nt * 16 + (l & 15);
        Wc2f[i] = f2b(wc2_val(k, n, c2_relW, c2_rootW));
    }
    for (int i = gid; i < 32768; i += gsz) {
        int j = i & 7, l = (i >> 3) & 63, rem = i >> 9;
        int nt = rem & 15, ks = rem >> 4;
        int k = ks * 32 + (l >> 4) * 8 + j;
        int n = nt * 16 + (l & 15);
        vW0f[i] = f2b(v_W0[k * 256 + n]);
    }
    for (int i = gid; i < 32768; i += gsz) {
        int j = i & 7, l = (i >> 3) & 63, rem = i >> 9;
        int nt = rem & 7, ks = rem >> 3;
        int k = ks * 32 + (l >> 4) * 8 + j;
        int n = nt * 16 + (l & 15);
        vW1f[i] = f2b(v_W1[k * 128 + n]);
    }
}

// ---------------------------------------------------------------------------
// mlp_body: 128 rows/block, 8 waves (512 thr). Swapped-operand MFMA:
//   A = weight fragment (same tables; A/B lane maps identical), B = activation.
//   D[row=quad*4+reg -> out-col n, col=l15 -> data row r] => packed b64 stores.
// TAIL: t = e@M -> tT (b64 global), col-sums -> fp32 atomics.
// root: e stored ROW-major to eR (b64 global), no LDS round-trip.
// ---------------------------------------------------------------------------
template<int NPB, int NODE0, int INOFF, int INDIM, bool TAIL>
__device__ __forceinline__ void mlp_body(
    int bid, const float* __restrict__ state,
    const unsigned short* __restrict__ W0b, const float* __restrict__ b0,
    const unsigned short* __restrict__ W1f, const float* __restrict__ b1,
    const unsigned short* __restrict__ Mf,
    unsigned short* __restrict__ tT, float* __restrict__ sumT,
    unsigned short* __restrict__ eR, int NR, char* smem)
{
    float* Xs = (float*)smem;                              // [128][9]
    unsigned short* hs = (unsigned short*)(smem + 4608);   // [128][264]
    unsigned short* esA = (unsigned short*)smem;           // TAIL: [128][136]

    const int t = threadIdx.x;
    const int lane = t & 63;
    const int w = t >> 6;            // 8 waves, wave w -> rows w*16..+15
    const int l15 = lane & 15;
    const int quad = lane >> 4;
    const int row0 = bid * 128;

    for (int idx = t; idx < 1024; idx += 512) {
        int r = idx & 127, j = idx >> 7;
        float v = 0.f;
        if (j < INDIM) {
            int row = row0 + r;
            int b = row / NPB;
            int n = row - b * NPB + NODE0;
            v = state[((size_t)b * NSTATE + n) * DIN + INOFF + j];
        }
        Xs[r * 9 + j] = v;
    }
    __syncthreads();

    // ---- layer 1 (swapped): lane holds h[r=l15][n=nt*16+quad*4+reg] ----
    {
        bf16x8 bx = {};
        if (quad == 0) {
            #pragma unroll
            for (int j = 0; j < INDIM; ++j)
                bx[j] = (short)f2b(Xs[(w * 16 + l15) * 9 + j]);
        }
        #pragma unroll
        for (int nt = 0; nt < 16; ++nt) {
            bf16x8 aw = {};
            if (quad == 0)
                aw = *(const bf16x8*)(W0b + (nt * 16 + l15) * 8);
            float4 bb = *(const float4*)(b0 + nt * 16 + quad * 4);
            f32x4 c = {bb.x, bb.y, bb.z, bb.w};
            c = __builtin_amdgcn_mfma_f32_16x16x32_bf16(aw, bx, c, 0, 0, 0);
            uint2 pv = {pack2(c[0], c[1]), pack2(c[2], c[3])};
            *(uint2*)(hs + (w * 16 + l15) * 264 + nt * 16 + quad * 4) = pv;
        }
    }
    __syncthreads();

    // ---- layer 2 (swapped): lane holds e[r=l15][n=nt*16+quad*4+reg] ----
    f32x4 acc[8];
    #pragma unroll
    for (int nt = 0; nt < 8; ++nt) {
        float4 bb = *(const float4*)(b1 + nt * 16 + quad * 4);
        acc[nt] = (f32x4){bb.x, bb.y, bb.z, bb.w};
    }
    #pragma unroll
    for (int ks = 0; ks < 8; ++ks) {
        bf16x8 bh = *(const bf16x8*)(hs + (w * 16 + l15) * 264 + ks * 32 + quad * 8);
        #pragma unroll
        for (int nt = 0; nt < 8; ++nt) {
            bf16x8 aw = *(const bf16x8*)(W1f + ((ks * 8 + nt) * 64 + lane) * 8);
            acc[nt] = __builtin_amdgcn_mfma_f32_16x16x32_bf16(aw, bh, acc[nt], 0, 0, 0);
        }
    }

    if constexpr (TAIL) {
        __syncthreads();   // hs dead before esA aliases it
        #pragma unroll
        for (int nt = 0; nt < 8; ++nt) {
            uint2 pv = {pack2(acc[nt][0], acc[nt][1]), pack2(acc[nt][2], acc[nt][3])};
            *(uint2*)(esA + (w * 16 + l15) * 136 + nt * 16 + quad * 4) = pv;
        }
        __syncthreads();

        // t = e @ M (unswapped, R5-verified): D[col=l15 -> t-col, row -> r-part]
        f32x4 tacc[2] = {{0.f,0.f,0.f,0.f},{0.f,0.f,0.f,0.f}};
        #pragma unroll
        for (int ks = 0; ks < 4; ++ks) {
            bf16x8 ae = *(const bf16x8*)(esA + (w * 16 + l15) * 136 + ks * 32 + quad * 8);
            #pragma unroll
            for (int nt = 0; nt < 2; ++nt) {
                bf16x8 bm = *(const bf16x8*)(Mf + ((ks * 2 + nt) * 64 + lane) * 8);
                tacc[nt] = __builtin_amdgcn_mfma_f32_16x16x32_bf16(ae, bm, tacc[nt], 0, 0, 0);
            }
        }
        #pragma unroll
        for (int nt = 0; nt < 2; ++nt) {
            uint2 pv = {pack2n(tacc[nt][0], tacc[nt][1]), pack2n(tacc[nt][2], tacc[nt][3])};
            *(uint2*)(tT + (size_t)(nt * 16 + l15) * NR + row0 + w * 16 + quad * 4) = pv;
        }

        // col-sums, all 512 threads: c = t&127, 32-row segment each
        {
            int c = t & 127, seg = t >> 7;
            int rbeg = seg * 32;
            float s = 0.f;
            int bcur = (row0 + rbeg) / NPB;
            #pragma unroll 8
            for (int r = rbeg; r < rbeg + 32; ++r) {
                int b = (row0 + r) / NPB;
                if (b != bcur) {
                    atomicAdd(&sumT[(size_t)c * BATCH + bcur], s);
                    s = 0.f; bcur = b;
                }
                s += b2f(esA[r * 136 + c]);
            }
            atomicAdd(&sumT[(size_t)c * BATCH + bcur], s);
        }
    } else {
        // root: direct row-major global store eR[row][n]
        #pragma unroll
        for (int nt = 0; nt < 8; ++nt) {
            uint2 pv = {pack2(acc[nt][0], acc[nt][1]), pack2(acc[nt][2], acc[nt][3])};
            *(uint2*)(eR + (size_t)(row0 + w * 16 + l15) * 128 + nt * 16 + quad * 4) = pv;
        }
    }
}

__global__ __launch_bounds__(512, 4) void k_mlpA(
    const float* __restrict__ state,
    const unsigned short* __restrict__ W0b_h, const float* __restrict__ b0_h,
    const unsigned short* __restrict__ W1f_h, const float* __restrict__ b1_h,
    const unsigned short* __restrict__ Mf_h, unsigned short* __restrict__ tT_h,
    float* __restrict__ shT,
    const unsigned short* __restrict__ W0b_o, const float* __restrict__ b0_o,
    const unsigned short* __restrict__ W1f_o, const float* __restrict__ b1_o,
    const unsigned short* __restrict__ Mf_o, unsigned short* __restrict__ tT_o,
    float* __restrict__ soT,
    const unsigned short* __restrict__ W0b_r, const float* __restrict__ b0_r,
    const unsigned short* __restrict__ W1f_r, const float* __restrict__ b1_r,
    unsigned short* __restrict__ eR)
{
    __shared__ __align__(16) char smem[4608 + 128 * 264 * 2];
    int bid = blockIdx.x;
    if (bid < 1280)
        mlp_body<20, 0, 6, 7, true>(bid, state, W0b_h, b0_h, W1f_h, b1_h,
                                    Mf_h, tT_h, shT, nullptr, 163840, smem);
    else if (bid < 1920)
        mlp_body<10, 20, 6, 7, true>(bid - 1280, state, W0b_o, b0_o, W1f_o, b1_o,
                                     Mf_o, tT_o, soT, nullptr, 81920, smem);
    else
        mlp_body<1, 0, 0, 6, false>(bid - 1920, state, W0b_r, b0_r, W1f_r, b1_r,
                                    nullptr, nullptr, nullptr, eR, 8192, smem);
}

// ---------------------------------------------------------------------------
// k_u2: [xr|ch|co](96) = U(384) @ Wcat + bcat via MFMA; 32 b/block.
// er now read ROW-major (coalesced dwordx4).
// ---------------------------------------------------------------------------
__global__ __launch_bounds__(256) void k_u2(
    const unsigned short* __restrict__ eR,
    const float* __restrict__ shT, const float* __restrict__ soT,
    const unsigned short* __restrict__ Wcatf, const float* __restrict__ bcat,
    unsigned short* __restrict__ xrT, float* __restrict__ chT, float* __restrict__ coT)
{
    __shared__ __align__(16) unsigned short Ub[32 * 400];   // [b][k], pitch 400
    const int t = threadIdx.x, lane = t & 63, w = t >> 6;
    const int l15 = lane & 15, quad = lane >> 4;
    const int b0 = blockIdx.x * 32;

    {   // er rows: 8 threads per b, 32B each
        int b = t >> 3, q = t & 7;
        const uint4* src = (const uint4*)(eR + (size_t)(b0 + b) * 128 + q * 16);
        uint4 v0 = src[0], v1 = src[1];
        uint4* dst = (uint4*)(Ub + b * 400 + q * 16);
        dst[0] = v0; dst[1] = v1;
    }
    for (int idx = t; idx < 8192; idx += 256) {
        int kk = idx >> 5, b = idx & 31;
        float v = (kk < 128) ? shT[(size_t)kk * BATCH + b0 + b]
                             : soT[(size_t)(kk - 128) * BATCH + b0 + b];
        Ub[b * 400 + 128 + kk] = f2b(v);
    }
    __syncthreads();

    const int mt = w >> 1, ntg = (w & 1) * 3;
    f32x4 acc[3];
    #pragma unroll
    for (int q = 0; q < 3; ++q) {
        float bias = bcat[(ntg + q) * 16 + l15];
        acc[q] = (f32x4){bias, bias, bias, bias};
    }
    #pragma unroll
    for (int ks = 0; ks < 12; ++ks) {
        bf16x8 a = *(const bf16x8*)(Ub + (mt * 16 + l15) * 400 + ks * 32 + quad * 8);
        #pragma unroll
        for (int q = 0; q < 3; ++q) {
            bf16x8 bw = *(const bf16x8*)(Wcatf + ((ks * 6 + ntg + q) * 64 + lane) * 8);
            acc[q] = __builtin_amdgcn_mfma_f32_16x16x32_bf16(a, bw, acc[q], 0, 0, 0);
        }
    }
    int brow = b0 + mt * 16 + quad * 4;
    #pragma unroll
    for (int q = 0; q < 3; ++q) {
        int n = (ntg + q) * 16 + l15;
        #pragma unroll
        for (int reg = 0; reg < 4; ++reg) {
            float v = acc[q][reg];
            int b = brow + reg;
            if (n < 32)      xrT[(size_t)n * BATCH + b] = f2b(fmaxf(v, 0.f));
            else if (n < 64) chT[(size_t)(n - 32) * BATCH + b] = v;
            else             coT[(size_t)(n - 64) * BATCH + b] = v;
        }
    }
}

// ---------------------------------------------------------------------------
// k_sM: s2[b][m] = sum_n relu(c[b][m] + t[b,n][m]); h and o merged.
// ---------------------------------------------------------------------------
__global__ __launch_bounds__(256) void k_sM(
    const unsigned short* __restrict__ tT_h, const unsigned short* __restrict__ tT_o,
    const float* __restrict__ chT, const float* __restrict__ coT,
    unsigned short* __restrict__ s2hT, unsigned short* __restrict__ s2oT)
{
    int bid = blockIdx.x;
    if (bid < 1024) {
        int gid = bid * 256 + threadIdx.x;
        int b = gid & (BATCH - 1), m = gid >> 13;
        const unsigned short* p = tT_h + (size_t)m * 163840 + b * 20;
        float c = chT[(size_t)m * BATCH + b];
        float s = 0.f;
        #pragma unroll
        for (int n = 0; n < 20; ++n) s += fmaxf(c + b2f(p[n]), 0.f);
        s2hT[(size_t)m * BATCH + b] = f2b(s);
    } else {
        int gid = (bid - 1024) * 256 + threadIdx.x;
        int b = gid & (BATCH - 1), m = gid >> 13;
        const unsigned short* p = tT_o + (size_t)m * 81920 + b * 10;
        float c = coT[(size_t)m * BATCH + b];
        float s = 0.f;
        #pragma unroll
        for (int n = 0; n < 10; ++n) s += fmaxf(c + b2f(p[n]), 0.f);
        s2oT[(size_t)m * BATCH + b] = f2b(s);
    }
}

// ---------------------------------------------------------------------------
// k_v: fused c2 + value-MLP via MFMA (R5-verified). 32 b/block, 256 blocks.
// ---------------------------------------------------------------------------
__global__ __launch_bounds__(256) void k_v(
    const unsigned short* __restrict__ xrT, const unsigned short* __restrict__ s2hT,
    const unsigned short* __restrict__ s2oT,
    const unsigned short* __restrict__ Wc2f, const float* __restrict__ bc2,
    const unsigned short* __restrict__ vW0f, const float* __restrict__ vb0,
    const unsigned short* __restrict__ vW1f, const float* __restrict__ vb1,
    const float* __restrict__ vW2, const float* __restrict__ vb2,
    float* __restrict__ out)
{
    __shared__ __align__(16) unsigned short Vb[32 * 104];
    __shared__ __align__(16) unsigned short Hb[32 * 136];
    __shared__ __align__(16) unsigned short V1b[32 * 264];
    __shared__ __align__(16) float V2b[32 * 132];
    const int t = threadIdx.x, lane = t & 63, w = t >> 6;
    const int l15 = lane & 15, quad = lane >> 4;
    const int b0 = blockIdx.x * 32;
    const int mt = w >> 1, nh = w & 1;
    const int rowb = mt * 16 + quad * 4;

    for (int idx = t; idx < 32 * 96; idx += 256) {
        int k = idx >> 5, b = idx & 31;
        unsigned short v;
        if (k < 32)      v = xrT[(size_t)k * BATCH + b0 + b];
        else if (k < 64) v = s2hT[(size_t)(k - 32) * BATCH + b0 + b];
        else             v = s2oT[(size_t)(k - 64) * BATCH + b0 + b];
        Vb[b * 104 + k] = v;
    }
    __syncthreads();

    { // c2
        const int ntg = nh * 4;
        f32x4 acc[4];
        #pragma unroll
        for (int q = 0; q < 4; ++q) {
            float bias = bc2[(ntg + q) * 16 + l15];
            acc[q] = (f32x4){bias, bias, bias, bias};
        }
        #pragma unroll
        for (int ks = 0; ks < 3; ++ks) {
            bf16x8 a = *(const bf16x8*)(Vb + (mt * 16 + l15) * 104 + ks * 32 + quad * 8);
            #pragma unroll
            for (int q = 0; q < 4; ++q) {
                bf16x8 bw = *(const bf16x8*)(Wc2f + ((ks * 8 + ntg + q) * 64 + lane) * 8);
                acc[q] = __builtin_amdgcn_mfma_f32_16x16x32_bf16(a, bw, acc[q], 0, 0, 0);
            }
        }
        #pragma unroll
        for (int q = 0; q < 4; ++q)
            #pragma unroll
            for (int reg = 0; reg < 4; ++reg)
                Hb[(rowb + reg) * 136 + (ntg + q) * 16 + l15] = f2b(fmaxf(acc[q][reg], 0.f));
    }
    __syncthreads();

    { // v1
        const int ntg = nh * 8;
        f32x4 acc[8];
        #pragma unroll
        for (int q = 0; q < 8; ++q) {
            float bias = vb0[(ntg + q) * 16 + l15];
            acc[q] = (f32x4){bias, bias, bias, bias};
        }
        #pragma unroll
        for (int ks = 0; ks < 4; ++ks) {
            bf16x8 a = *(const bf16x8*)(Hb + (mt * 16 + l15) * 136 + ks * 32 + quad * 8);
            #pragma unroll
            for (int q = 0; q < 8; ++q) {
                bf16x8 bw = *(const bf16x8*)(vW0f + ((ks * 16 + ntg + q) * 64 + lane) * 8);
                acc[q] = __builtin_amdgcn_mfma_f32_16x16x32_bf16(a, bw, acc[q], 0, 0, 0);
            }
        }
        __syncthreads();
        #pragma unroll
        for (int q = 0; q < 8; ++q)
            #pragma unroll
            for (int reg = 0; reg < 4; ++reg)
                V1b[(rowb + reg) * 264 + (ntg + q) * 16 + l15] = f2b(fmaxf(acc[q][reg], 0.f));
    }
    __syncthreads();

    { // v2
        const int ntg = nh * 4;
        f32x4 acc[4];
        #pragma unroll
        for (int q = 0; q < 4; ++q) {
            float bias = vb1[(ntg + q) * 16 + l15];
            acc[q] = (f32x4){bias, bias, bias, bias};
        }
        #pragma unroll
        for (int ks = 0; ks < 8; ++ks) {
            bf16x8 a = *(const bf16x8*)(V1b + (mt * 16 + l15) * 264 + ks * 32 + quad * 8);
            #pragma unroll
            for (int q = 0; q < 4; ++q) {
                bf16x8 bw = *(const bf16x8*)(vW1f + ((ks * 8 + ntg + q) * 64 + lane) * 8);
                acc[q] = __builtin_amdgcn_mfma_f32_16x16x32_bf16(a, bw, acc[q], 0, 0, 0);
            }
        }
        #pragma unroll
        for (int q = 0; q < 4; ++q)
            #pragma unroll
            for (int reg = 0; reg < 4; ++reg)
                V2b[(rowb + reg) * 132 + (ntg + q) * 16 + l15] = fmaxf(acc[q][reg], 0.f);
    }
    __syncthreads();

    if (t < 32) {
        float acc = vb2[0];
        for (int k = 0; k < 128; ++k)
            acc = fmaf(V2b[t * 132 + k], vW2[k], acc);
        out[b0 + t] = acc;
    }
}

// ---------------------------------------------------------------------------
extern "C" void kernel_launch(void* const* d_in, const int* in_sizes, int n_in,
                              void* d_out, int out_size, void* d_ws, size_t ws_size,
                              hipStream_t stream)
{
    const float* state   = (const float*)d_in[0];
    const float* wr_W0   = (const float*)d_in[2];
    const float* wr_b0   = (const float*)d_in[3];
    const float* wr_W1   = (const float*)d_in[4];
    const float* wr_b1   = (const float*)d_in[5];
    const float* wh_W0   = (const float*)d_in[6];
    const float* wh_b0   = (const float*)d_in[7];
    const float* wh_W1   = (const float*)d_in[8];
    const float* wh_b1   = (const float*)d_in[9];
    const float* wo_W0   = (const float*)d_in[10];
    const float* wo_b0   = (const float*)d_in[11];
    const float* wo_W1   = (const float*)d_in[12];
    const float* wo_b1   = (const float*)d_in[13];
    const float* c1_relW = (const float*)d_in[14];
    const float* c1_relb = (const float*)d_in[15];
    const float* c1_rootW= (const float*)d_in[16];
    const float* c2_relW = (const float*)d_in[17];
    const float* c2_relb = (const float*)d_in[18];
    const float* c2_rootW= (const float*)d_in[19];
    const float* v_W0    = (const float*)d_in[20];
    const float* v_b0    = (const float*)d_in[21];
    const float* v_W1    = (const float*)d_in[22];
    const float* v_b1    = (const float*)d_in[23];
    const float* v_W2    = (const float*)d_in[24];
    const float* v_b2    = (const float*)d_in[25];

    char* ws = (char*)d_ws;
    size_t off = 0;
    auto alloc = [&](size_t bytes) -> char* {
        char* p = ws + off;
        off = (off + bytes + 255) & ~(size_t)255;
        return p;
    };
    float* shT  = (float*)alloc((size_t)128 * BATCH * 4);          // fp32 atomic sums
    float* soT  = (float*)alloc((size_t)128 * BATCH * 4);          // contiguous with shT
    unsigned short* tT_h = (unsigned short*)alloc((size_t)32 * 163840 * 2);
    unsigned short* tT_o = (unsigned short*)alloc((size_t)32 * 81920 * 2);
    unsigned short* eR   = (unsigned short*)alloc((size_t)BATCH * 128 * 2);   // row-major
    unsigned short* xrT  = (unsigned short*)alloc((size_t)32 * BATCH * 2);
    float* chT  = (float*)alloc((size_t)32 * BATCH * 4);
    float* coT  = (float*)alloc((size_t)32 * BATCH * 4);
    unsigned short* s2hT = (unsigned short*)alloc((size_t)32 * BATCH * 2);
    unsigned short* s2oT = (unsigned short*)alloc((size_t)32 * BATCH * 2);
    float* bcat = (float*)alloc(96 * 4);
    float* bc2  = (float*)alloc(128 * 4);
    unsigned short* W0b_h = (unsigned short*)alloc(2048 * 2);
    unsigned short* W0b_o = (unsigned short*)alloc(2048 * 2);
    unsigned short* W0b_r = (unsigned short*)alloc(2048 * 2);
    unsigned short* W1f_h = (unsigned short*)alloc(32768 * 2);
    unsigned short* W1f_o = (unsigned short*)alloc(32768 * 2);
    unsigned short* W1f_r = (unsigned short*)alloc(32768 * 2);
    unsigned short* Mf_h  = (unsigned short*)alloc(4096 * 2);
    unsigned short* Mf_o  = (unsigned short*)alloc(4096 * 2);
    unsigned short* Wcatf = (unsigned short*)alloc(36864 * 2);
    unsigned short* Wc2f  = (unsigned short*)alloc(12288 * 2);
    unsigned short* vW0f  = (unsigned short*)alloc(32768 * 2);
    unsigned short* vW1f  = (unsigned short*)alloc(32768 * 2);
    (void)ws_size; (void)in_sizes; (void)n_in; (void)out_size;

    hipMemsetAsync(shT, 0, (size_t)2 * 128 * BATCH * 4, stream);

    k_prep<<<64, 256, 0, stream>>>(c1_relW, c1_relb, c1_rootW, c2_relW, c2_relb, c2_rootW,
                                   wh_W0, wh_W1, wo_W0, wo_W1, wr_W0, wr_W1, v_W0, v_W1,
                                   bcat, bc2, W0b_h, W0b_o, W0b_r, W1f_h, W1f_o, W1f_r,
                                   Mf_h, Mf_o, Wcatf, Wc2f, vW0f, vW1f);

    k_mlpA<<<1984, 512, 0, stream>>>(state,
                                     W0b_h, wh_b0, W1f_h, wh_b1, Mf_h, tT_h, shT,
                                     W0b_o, wo_b0, W1f_o, wo_b1, Mf_o, tT_o, soT,
                                     W0b_r, wr_b0, W1f_r, wr_b1, eR);
    k_u2<<<256, 256, 0, stream>>>(eR, shT, soT, Wcatf, bcat, xrT, chT, coT);
    k_sM<<<2048, 256, 0, stream>>>(tT_h, tT_o, chT, coT, s2hT, s2oT);
    k_v<<<256, 256, 0, stream>>>(xrT, s2hT, s2oT, Wc2f, bc2, vW0f, v_b0, vW1f, v_b1,
                                 v_W2, v_b2, (float*)d_out);
}

// Round 7
// 290.991 us; speedup vs baseline: 2.0754x; 1.0421x over previous
//
#include <hip/hip_runtime.h>
#include <hip/hip_bf16.h>
#include <stdint.h>

#define BATCH 8192
#define NSTATE 30
#define DIN 13
#define E1 256
#define E2 128

typedef short bf16x8 __attribute__((ext_vector_type(8)));
typedef float f32x4 __attribute__((ext_vector_type(4)));

// f32 -> bf16 bits, round-to-nearest-even
__device__ __forceinline__ unsigned short f2b(float f) {
    unsigned u = __float_as_uint(f);
    u += 0x7FFFu + ((u >> 16) & 1u);
    return (unsigned short)(u >> 16);
}
__device__ __forceinline__ float b2f(unsigned short b) {
    return __uint_as_float((unsigned)b << 16);
}
__device__ __forceinline__ unsigned pack2(float a, float b) {     // relu+pack
    return ((unsigned)f2b(fmaxf(b, 0.f)) << 16) | f2b(fmaxf(a, 0.f));
}
__device__ __forceinline__ unsigned pack2n(float a, float b) {    // pack only
    return ((unsigned)f2b(b) << 16) | f2b(a);
}

// combined conv1 weight values (derived R1, verified)
__device__ __forceinline__ float wcat_val(int k, int m, const float* relW, const float* rootW) {
    int part = k >> 7, c = k & 127, grp = m >> 5, mm = m & 31;
    int off = c * 32 + mm;
    if (part == 0) return (grp == 0) ? rootW[4096 + off] + rootW[8192 + off]
                        : (grp == 1) ? relW[off] : relW[3*4096 + off];
    if (part == 1) return (grp == 0) ? relW[1*4096 + off]
                        : (grp == 1) ? relW[6*4096 + off] : relW[5*4096 + off];
    return (grp == 0) ? relW[2*4096 + off]
         : (grp == 1) ? relW[4*4096 + off] : relW[7*4096 + off];
}
__device__ __forceinline__ float wc2_val(int k, int n, const float* relW, const float* rootW) {
    int grp = k >> 5, kk = k & 31;
    int off = kk * 128 + n;
    if (grp == 0) return rootW[4096 + off] + rootW[8192 + off];
    if (grp == 1) return relW[4096 + off];
    return relW[8192 + off];
}

// ---------------------------------------------------------------------------
// k_prep: bias vectors + ALL bf16 MFMA fragment tables (verified decode):
//   entry i -> j=i&7, l=(i>>3)&63, k = ks*32+(l>>4)*8+j, n = nt*16+(l&15)
// ---------------------------------------------------------------------------
__global__ void k_prep(const float* __restrict__ c1_relW, const float* __restrict__ c1_relb,
                       const float* __restrict__ c1_rootW,
                       const float* __restrict__ c2_relW, const float* __restrict__ c2_relb,
                       const float* __restrict__ c2_rootW,
                       const float* __restrict__ wh_W0, const float* __restrict__ wh_W1,
                       const float* __restrict__ wo_W0, const float* __restrict__ wo_W1,
                       const float* __restrict__ wr_W0, const float* __restrict__ wr_W1,
                       const float* __restrict__ v_W0, const float* __restrict__ v_W1,
                       float* __restrict__ bcat, float* __restrict__ bc2,
                       unsigned short* __restrict__ W0b_h, unsigned short* __restrict__ W0b_o,
                       unsigned short* __restrict__ W0b_r,
                       unsigned short* __restrict__ W1f_h, unsigned short* __restrict__ W1f_o,
                       unsigned short* __restrict__ W1f_r,
                       unsigned short* __restrict__ Mf_h, unsigned short* __restrict__ Mf_o,
                       unsigned short* __restrict__ Wcatf, unsigned short* __restrict__ Wc2f,
                       unsigned short* __restrict__ vW0f, unsigned short* __restrict__ vW1f)
{
    int gid = blockIdx.x * blockDim.x + threadIdx.x;
    int gsz = gridDim.x * blockDim.x;

    for (int i = gid; i < 96; i += gsz) {
        int grp = i >> 5, mm = i & 31;
        float v;
        if (grp == 0)      v = c1_relb[32 + mm] + c1_relb[64 + mm];
        else if (grp == 1) v = c1_relb[mm] + c1_relb[128 + mm] + c1_relb[192 + mm];
        else               v = c1_relb[96 + mm] + c1_relb[160 + mm] + c1_relb[224 + mm];
        bcat[i] = v;
    }
    for (int i = gid; i < 128; i += gsz) bc2[i] = c2_relb[128 + i] + c2_relb[256 + i];

    for (int i = gid; i < 2048; i += gsz) {
        int n = i >> 3, j = i & 7;
        W0b_h[i] = (j < 7) ? f2b(wh_W0[j * 256 + n]) : 0;
        W0b_o[i] = (j < 7) ? f2b(wo_W0[j * 256 + n]) : 0;
        W0b_r[i] = (j < 6) ? f2b(wr_W0[j * 256 + n]) : 0;
    }
    for (int i = gid; i < 32768; i += gsz) {
        int j = i & 7, l = (i >> 3) & 63, nt = (i >> 9) & 7, ks = i >> 12;
        int k = ks * 32 + (l >> 4) * 8 + j;
        int n = nt * 16 + (l & 15);
        W1f_h[i] = f2b(wh_W1[k * 128 + n]);
        W1f_o[i] = f2b(wo_W1[k * 128 + n]);
        W1f_r[i] = f2b(wr_W1[k * 128 + n]);
    }
    for (int i = gid; i < 4096; i += gsz) {
        int j = i & 7, l = (i >> 3) & 63, nt = (i >> 9) & 1, ks = i >> 10;
        int k = ks * 32 + (l >> 4) * 8 + j;
        int n = nt * 16 + (l & 15);
        int i0 = k * 32 + n;
        Mf_h[i] = f2b(c1_rootW[i0] + c1_rootW[4*4096 + i0] + c1_rootW[6*4096 + i0] - c1_relW[6*4096 + i0]);
        Mf_o[i] = f2b(c1_rootW[3*4096 + i0] + c1_rootW[5*4096 + i0] + c1_rootW[7*4096 + i0] - c1_relW[7*4096 + i0]);
    }
    for (int i = gid; i < 36864; i += gsz) {
        int j = i & 7, l = (i >> 3) & 63, rem = i >> 9;
        int nt = rem % 6, ks = rem / 6;
        int k = ks * 32 + (l >> 4) * 8 + j;
        int n = nt * 16 + (l & 15);
        Wcatf[i] = f2b(wcat_val(k, n, c1_relW, c1_rootW));
    }
    for (int i = gid; i < 12288; i += gsz) {
        int j = i & 7, l = (i >> 3) & 63, rem = i >> 9;
        int nt = rem & 7, ks = rem >> 3;
        int k = ks * 32 + (l >> 4) * 8 + j;
        int n = nt * 16 + (l & 15);
        Wc2f[i] = f2b(wc2_val(k, n, c2_relW, c2_rootW));
    }
    for (int i = gid; i < 32768; i += gsz) {
        int j = i & 7, l = (i >> 3) & 63, rem = i >> 9;
        int nt = rem & 15, ks = rem >> 4;
        int k = ks * 32 + (l >> 4) * 8 + j;
        int n = nt * 16 + (l & 15);
        vW0f[i] = f2b(v_W0[k * 256 + n]);
    }
    for (int i = gid; i < 32768; i += gsz) {
        int j = i & 7, l = (i >> 3) & 63, rem = i >> 9;
        int nt = rem & 7, ks = rem >> 3;
        int k = ks * 32 + (l >> 4) * 8 + j;
        int n = nt * 16 + (l & 15);
        vW1f[i] = f2b(v_W1[k * 128 + n]);
    }
}

// ---------------------------------------------------------------------------
// mlp_block: persistent block, 8 tiles x 128 rows, 512 thr (8 waves).
// Weights staged to LDS ONCE per block; all fragment reads = ds_read_b128.
// Math identical to R6 (verified): swapped-operand L1/L2, unswapped t=e@M.
// LDS map: W0s@0 (4KB) | Mfs@4K (8KB) | W1s@12K (64KB) | Xs@76K (4.6KB)
//          hs@80.5K (67.6KB, esA aliases it)
// ---------------------------------------------------------------------------
#define SM_W0   0
#define SM_MF   4096
#define SM_W1   12288
#define SM_XS   77824
#define SM_HS   82432
#define SM_SZ   (82432 + 128 * 264 * 2)

template<int NPB, int NODE0, int INOFF, int INDIM, bool TAIL>
__device__ __forceinline__ void mlp_block(
    int tile0, const float* __restrict__ state,
    const unsigned short* __restrict__ W0b_g, const float* __restrict__ b0,
    const unsigned short* __restrict__ W1f_g, const float* __restrict__ b1,
    const unsigned short* __restrict__ Mf_g,
    unsigned short* __restrict__ tT, float* __restrict__ sumT,
    unsigned short* __restrict__ eR, int NR, char* smem)
{
    unsigned short* W0s = (unsigned short*)(smem + SM_W0);
    unsigned short* Mfs = (unsigned short*)(smem + SM_MF);
    unsigned short* W1s = (unsigned short*)(smem + SM_W1);
    float* Xs           = (float*)(smem + SM_XS);            // [128][9]
    unsigned short* hs  = (unsigned short*)(smem + SM_HS);   // [128][264]
    unsigned short* esA = (unsigned short*)(smem + SM_HS);   // alias [128][136]

    const int t = threadIdx.x;
    const int lane = t & 63;
    const int w = t >> 6;
    const int l15 = lane & 15;
    const int quad = lane >> 4;

    // ---- stage weights to LDS once ----
    {
        if (t < 256) ((uint4*)W0s)[t] = ((const uint4*)W0b_g)[t];
        #pragma unroll
        for (int i = 0; i < 8; ++i)
            ((uint4*)W1s)[t + 512 * i] = ((const uint4*)W1f_g)[t + 512 * i];
        if constexpr (TAIL) {
            if (t < 512) ((uint4*)Mfs)[t] = ((const uint4*)Mf_g)[t];
        }
    }
    __syncthreads();

    for (int tl = 0; tl < 8; ++tl) {
        const int row0 = (tile0 + tl) * 128;

        for (int idx = t; idx < 1024; idx += 512) {
            int r = idx & 127, j = idx >> 7;
            float v = 0.f;
            if (j < INDIM) {
                int row = row0 + r;
                int b = row / NPB;
                int n = row - b * NPB + NODE0;
                v = state[((size_t)b * NSTATE + n) * DIN + INOFF + j];
            }
            Xs[r * 9 + j] = v;
        }
        __syncthreads();

        // ---- layer 1 (swapped): lane holds h[r=l15][n=nt*16+quad*4+reg] ----
        {
            bf16x8 bx = {};
            if (quad == 0) {
                #pragma unroll
                for (int j = 0; j < INDIM; ++j)
                    bx[j] = (short)f2b(Xs[(w * 16 + l15) * 9 + j]);
            }
            #pragma unroll
            for (int nt = 0; nt < 16; ++nt) {
                bf16x8 aw = {};
                if (quad == 0)
                    aw = *(const bf16x8*)(W0s + (nt * 16 + l15) * 8);
                float4 bb = *(const float4*)(b0 + nt * 16 + quad * 4);
                f32x4 c = {bb.x, bb.y, bb.z, bb.w};
                c = __builtin_amdgcn_mfma_f32_16x16x32_bf16(aw, bx, c, 0, 0, 0);
                uint2 pv = {pack2(c[0], c[1]), pack2(c[2], c[3])};
                *(uint2*)(hs + (w * 16 + l15) * 264 + nt * 16 + quad * 4) = pv;
            }
        }
        __syncthreads();

        // ---- layer 2 (swapped): lane holds e[r=l15][n=nt*16+quad*4+reg] ----
        f32x4 acc[8];
        #pragma unroll
        for (int nt = 0; nt < 8; ++nt) {
            float4 bb = *(const float4*)(b1 + nt * 16 + quad * 4);
            acc[nt] = (f32x4){bb.x, bb.y, bb.z, bb.w};
        }
        #pragma unroll
        for (int ks = 0; ks < 8; ++ks) {
            bf16x8 bh = *(const bf16x8*)(hs + (w * 16 + l15) * 264 + ks * 32 + quad * 8);
            #pragma unroll
            for (int nt = 0; nt < 8; ++nt) {
                bf16x8 aw = *(const bf16x8*)(W1s + ((ks * 8 + nt) * 64 + lane) * 8);
                acc[nt] = __builtin_amdgcn_mfma_f32_16x16x32_bf16(aw, bh, acc[nt], 0, 0, 0);
            }
        }

        if constexpr (TAIL) {
            __syncthreads();   // hs reads done before esA overwrites
            #pragma unroll
            for (int nt = 0; nt < 8; ++nt) {
                uint2 pv = {pack2(acc[nt][0], acc[nt][1]), pack2(acc[nt][2], acc[nt][3])};
                *(uint2*)(esA + (w * 16 + l15) * 136 + nt * 16 + quad * 4) = pv;
            }
            __syncthreads();

            // t = e @ M (unswapped): A = e frag, B = Mf frag (from LDS)
            f32x4 tacc[2] = {{0.f,0.f,0.f,0.f},{0.f,0.f,0.f,0.f}};
            #pragma unroll
            for (int ks = 0; ks < 4; ++ks) {
                bf16x8 ae = *(const bf16x8*)(esA + (w * 16 + l15) * 136 + ks * 32 + quad * 8);
                #pragma unroll
                for (int nt = 0; nt < 2; ++nt) {
                    bf16x8 bm = *(const bf16x8*)(Mfs + ((ks * 2 + nt) * 64 + lane) * 8);
                    tacc[nt] = __builtin_amdgcn_mfma_f32_16x16x32_bf16(ae, bm, tacc[nt], 0, 0, 0);
                }
            }
            #pragma unroll
            for (int nt = 0; nt < 2; ++nt) {
                uint2 pv = {pack2n(tacc[nt][0], tacc[nt][1]), pack2n(tacc[nt][2], tacc[nt][3])};
                *(uint2*)(tT + (size_t)(nt * 16 + l15) * NR + row0 + w * 16 + quad * 4) = pv;
            }

            // col-sums: c = t&127, 32-row segment each, fp32 atomics
            {
                int c = t & 127, seg = t >> 7;
                int rbeg = seg * 32;
                float s = 0.f;
                int bcur = (row0 + rbeg) / NPB;
                #pragma unroll 8
                for (int r = rbeg; r < rbeg + 32; ++r) {
                    int b = (row0 + r) / NPB;
                    if (b != bcur) {
                        atomicAdd(&sumT[(size_t)c * BATCH + bcur], s);
                        s = 0.f; bcur = b;
                    }
                    s += b2f(esA[r * 136 + c]);
                }
                atomicAdd(&sumT[(size_t)c * BATCH + bcur], s);
            }
        } else {
            #pragma unroll
            for (int nt = 0; nt < 8; ++nt) {
                uint2 pv = {pack2(acc[nt][0], acc[nt][1]), pack2(acc[nt][2], acc[nt][3])};
                *(uint2*)(eR + (size_t)(row0 + w * 16 + l15) * 128 + nt * 16 + quad * 4) = pv;
            }
        }
        __syncthreads();   // tile boundary: hs/esA safe to overwrite
    }
}

__global__ __launch_bounds__(512, 2) void k_mlpB(
    const float* __restrict__ state,
    const unsigned short* __restrict__ W0b_h, const float* __restrict__ b0_h,
    const unsigned short* __restrict__ W1f_h, const float* __restrict__ b1_h,
    const unsigned short* __restrict__ Mf_h, unsigned short* __restrict__ tT_h,
    float* __restrict__ shT,
    const unsigned short* __restrict__ W0b_o, const float* __restrict__ b0_o,
    const unsigned short* __restrict__ W1f_o, const float* __restrict__ b1_o,
    const unsigned short* __restrict__ Mf_o, unsigned short* __restrict__ tT_o,
    float* __restrict__ soT,
    const unsigned short* __restrict__ W0b_r, const float* __restrict__ b0_r,
    const unsigned short* __restrict__ W1f_r, const float* __restrict__ b1_r,
    unsigned short* __restrict__ eR)
{
    __shared__ __align__(16) char smem[SM_SZ];
    int bid = blockIdx.x;
    if (bid < 160)
        mlp_block<20, 0, 6, 7, true>(bid * 8, state, W0b_h, b0_h, W1f_h, b1_h,
                                     Mf_h, tT_h, shT, nullptr, 163840, smem);
    else if (bid < 240)
        mlp_block<10, 20, 6, 7, true>((bid - 160) * 8, state, W0b_o, b0_o, W1f_o, b1_o,
                                      Mf_o, tT_o, soT, nullptr, 81920, smem);
    else
        mlp_block<1, 0, 0, 6, false>((bid - 240) * 8, state, W0b_r, b0_r, W1f_r, b1_r,
                                     nullptr, nullptr, nullptr, eR, 8192, smem);
}

// ---------------------------------------------------------------------------
// k_u2: [xr|ch|co](96) = U(384) @ Wcat + bcat via MFMA; 32 b/block.
// ---------------------------------------------------------------------------
__global__ __launch_bounds__(256) void k_u2(
    const unsigned short* __restrict__ eR,
    const float* __restrict__ shT, const float* __restrict__ soT,
    const unsigned short* __restrict__ Wcatf, const float* __restrict__ bcat,
    unsigned short* __restrict__ xrT, float* __restrict__ chT, float* __restrict__ coT)
{
    __shared__ __align__(16) unsigned short Ub[32 * 400];
    const int t = threadIdx.x, lane = t & 63, w = t >> 6;
    const int l15 = lane & 15, quad = lane >> 4;
    const int b0 = blockIdx.x * 32;

    {
        int b = t >> 3, q = t & 7;
        const uint4* src = (const uint4*)(eR + (size_t)(b0 + b) * 128 + q * 16);
        uint4 v0 = src[0], v1 = src[1];
        uint4* dst = (uint4*)(Ub + b * 400 + q * 16);
        dst[0] = v0; dst[1] = v1;
    }
    for (int idx = t; idx < 8192; idx += 256) {
        int kk = idx >> 5, b = idx & 31;
        float v = (kk < 128) ? shT[(size_t)kk * BATCH + b0 + b]
                             : soT[(size_t)(kk - 128) * BATCH + b0 + b];
        Ub[b * 400 + 128 + kk] = f2b(v);
    }
    __syncthreads();

    const int mt = w >> 1, ntg = (w & 1) * 3;
    f32x4 acc[3];
    #pragma unroll
    for (int q = 0; q < 3; ++q) {
        float bias = bcat[(ntg + q) * 16 + l15];
        acc[q] = (f32x4){bias, bias, bias, bias};
    }
    #pragma unroll
    for (int ks = 0; ks < 12; ++ks) {
        bf16x8 a = *(const bf16x8*)(Ub + (mt * 16 + l15) * 400 + ks * 32 + quad * 8);
        #pragma unroll
        for (int q = 0; q < 3; ++q) {
            bf16x8 bw = *(const bf16x8*)(Wcatf + ((ks * 6 + ntg + q) * 64 + lane) * 8);
            acc[q] = __builtin_amdgcn_mfma_f32_16x16x32_bf16(a, bw, acc[q], 0, 0, 0);
        }
    }
    int brow = b0 + mt * 16 + quad * 4;
    #pragma unroll
    for (int q = 0; q < 3; ++q) {
        int n = (ntg + q) * 16 + l15;
        #pragma unroll
        for (int reg = 0; reg < 4; ++reg) {
            float v = acc[q][reg];
            int b = brow + reg;
            if (n < 32)      xrT[(size_t)n * BATCH + b] = f2b(fmaxf(v, 0.f));
            else if (n < 64) chT[(size_t)(n - 32) * BATCH + b] = v;
            else             coT[(size_t)(n - 64) * BATCH + b] = v;
        }
    }
}

// ---------------------------------------------------------------------------
// k_sM: s2[b][m] = sum_n relu(c[b][m] + t[b,n][m]); h and o merged.
// ---------------------------------------------------------------------------
__global__ __launch_bounds__(256) void k_sM(
    const unsigned short* __restrict__ tT_h, const unsigned short* __restrict__ tT_o,
    const float* __restrict__ chT, const float* __restrict__ coT,
    unsigned short* __restrict__ s2hT, unsigned short* __restrict__ s2oT)
{
    int bid = blockIdx.x;
    if (bid < 1024) {
        int gid = bid * 256 + threadIdx.x;
        int b = gid & (BATCH - 1), m = gid >> 13;
        const unsigned short* p = tT_h + (size_t)m * 163840 + b * 20;
        float c = chT[(size_t)m * BATCH + b];
        float s = 0.f;
        #pragma unroll
        for (int n = 0; n < 20; ++n) s += fmaxf(c + b2f(p[n]), 0.f);
        s2hT[(size_t)m * BATCH + b] = f2b(s);
    } else {
        int gid = (bid - 1024) * 256 + threadIdx.x;
        int b = gid & (BATCH - 1), m = gid >> 13;
        const unsigned short* p = tT_o + (size_t)m * 81920 + b * 10;
        float c = coT[(size_t)m * BATCH + b];
        float s = 0.f;
        #pragma unroll
        for (int n = 0; n < 10; ++n) s += fmaxf(c + b2f(p[n]), 0.f);
        s2oT[(size_t)m * BATCH + b] = f2b(s);
    }
}

// ---------------------------------------------------------------------------
// k_v: fused c2 + value-MLP via MFMA (verified). 32 b/block, 256 blocks.
// ---------------------------------------------------------------------------
__global__ __launch_bounds__(256) void k_v(
    const unsigned short* __restrict__ xrT, const unsigned short* __restrict__ s2hT,
    const unsigned short* __restrict__ s2oT,
    const unsigned short* __restrict__ Wc2f, const float* __restrict__ bc2,
    const unsigned short* __restrict__ vW0f, const float* __restrict__ vb0,
    const unsigned short* __restrict__ vW1f, const float* __restrict__ vb1,
    const float* __restrict__ vW2, const float* __restrict__ vb2,
    float* __restrict__ out)
{
    __shared__ __align__(16) unsigned short Vb[32 * 104];
    __shared__ __align__(16) unsigned short Hb[32 * 136];
    __shared__ __align__(16) unsigned short V1b[32 * 264];
    __shared__ __align__(16) float V2b[32 * 132];
    const int t = threadIdx.x, lane = t & 63, w = t >> 6;
    const int l15 = lane & 15, quad = lane >> 4;
    const int b0 = blockIdx.x * 32;
    const int mt = w >> 1, nh = w & 1;
    const int rowb = mt * 16 + quad * 4;

    for (int idx = t; idx < 32 * 96; idx += 256) {
        int k = idx >> 5, b = idx & 31;
        unsigned short v;
        if (k < 32)      v = xrT[(size_t)k * BATCH + b0 + b];
        else if (k < 64) v = s2hT[(size_t)(k - 32) * BATCH + b0 + b];
        else             v = s2oT[(size_t)(k - 64) * BATCH + b0 + b];
        Vb[b * 104 + k] = v;
    }
    __syncthreads();

    { // c2
        const int ntg = nh * 4;
        f32x4 acc[4];
        #pragma unroll
        for (int q = 0; q < 4; ++q) {
            float bias = bc2[(ntg + q) * 16 + l15];
            acc[q] = (f32x4){bias, bias, bias, bias};
        }
        #pragma unroll
        for (int ks = 0; ks < 3; ++ks) {
            bf16x8 a = *(const bf16x8*)(Vb + (mt * 16 + l15) * 104 + ks * 32 + quad * 8);
            #pragma unroll
            for (int q = 0; q < 4; ++q) {
                bf16x8 bw = *(const bf16x8*)(Wc2f + ((ks * 8 + ntg + q) * 64 + lane) * 8);
                acc[q] = __builtin_amdgcn_mfma_f32_16x16x32_bf16(a, bw, acc[q], 0, 0, 0);
            }
        }
        #pragma unroll
        for (int q = 0; q < 4; ++q)
            #pragma unroll
            for (int reg = 0; reg < 4; ++reg)
                Hb[(rowb + reg) * 136 + (ntg + q) * 16 + l15] = f2b(fmaxf(acc[q][reg], 0.f));
    }
    __syncthreads();

    { // v1
        const int ntg = nh * 8;
        f32x4 acc[8];
        #pragma unroll
        for (int q = 0; q < 8; ++q) {
            float bias = vb0[(ntg + q) * 16 + l15];
            acc[q] = (f32x4){bias, bias, bias, bias};
        }
        #pragma unroll
        for (int ks = 0; ks < 4; ++ks) {
            bf16x8 a = *(const bf16x8*)(Hb + (mt * 16 + l15) * 136 + ks * 32 + quad * 8);
            #pragma unroll
            for (int q = 0; q < 8; ++q) {
                bf16x8 bw = *(const bf16x8*)(vW0f + ((ks * 16 + ntg + q) * 64 + lane) * 8);
                acc[q] = __builtin_amdgcn_mfma_f32_16x16x32_bf16(a, bw, acc[q], 0, 0, 0);
            }
        }
        __syncthreads();
        #pragma unroll
        for (int q = 0; q < 8; ++q)
            #pragma unroll
            for (int reg = 0; reg < 4; ++reg)
                V1b[(rowb + reg) * 264 + (ntg + q) * 16 + l15] = f2b(fmaxf(acc[q][reg], 0.f));
    }
    __syncthreads();

    { // v2
        const int ntg = nh * 4;
        f32x4 acc[4];
        #pragma unroll
        for (int q = 0; q < 4; ++q) {
            float bias = vb1[(ntg + q) * 16 + l15];
            acc[q] = (f32x4){bias, bias, bias, bias};
        }
        #pragma unroll
        for (int ks = 0; ks < 8; ++ks) {
            bf16x8 a = *(const bf16x8*)(V1b + (mt * 16 + l15) * 264 + ks * 32 + quad * 8);
            #pragma unroll
            for (int q = 0; q < 4; ++q) {
                bf16x8 bw = *(const bf16x8*)(vW1f + ((ks * 8 + ntg + q) * 64 + lane) * 8);
                acc[q] = __builtin_amdgcn_mfma_f32_16x16x32_bf16(a, bw, acc[q], 0, 0, 0);
            }
        }
        #pragma unroll
        for (int q = 0; q < 4; ++q)
            #pragma unroll
            for (int reg = 0; reg < 4; ++reg)
                V2b[(rowb + reg) * 132 + (ntg + q) * 16 + l15] = fmaxf(acc[q][reg], 0.f);
    }
    __syncthreads();

    if (t < 32) {
        float acc = vb2[0];
        for (int k = 0; k < 128; ++k)
            acc = fmaf(V2b[t * 132 + k], vW2[k], acc);
        out[b0 + t] = acc;
    }
}

// ---------------------------------------------------------------------------
extern "C" void kernel_launch(void* const* d_in, const int* in_sizes, int n_in,
                              void* d_out, int out_size, void* d_ws, size_t ws_size,
                              hipStream_t stream)
{
    const float* state   = (const float*)d_in[0];
    const float* wr_W0   = (const float*)d_in[2];
    const float* wr_b0   = (const float*)d_in[3];
    const float* wr_W1   = (const float*)d_in[4];
    const float* wr_b1   = (const float*)d_in[5];
    const float* wh_W0   = (const float*)d_in[6];
    const float* wh_b0   = (const float*)d_in[7];
    const float* wh_W1   = (const float*)d_in[8];
    const float* wh_b1   = (const float*)d_in[9];
    const float* wo_W0   = (const float*)d_in[10];
    const float* wo_b0   = (const float*)d_in[11];
    const float* wo_W1   = (const float*)d_in[12];
    const float* wo_b1   = (const float*)d_in[13];
    const float* c1_relW = (const float*)d_in[14];
    const float* c1_relb = (const float*)d_in[15];
    const float* c1_rootW= (const float*)d_in[16];
    const float* c2_relW = (const float*)d_in[17];
    const float* c2_relb = (const float*)d_in[18];
    const float* c2_rootW= (const float*)d_in[19];
    const float* v_W0    = (const float*)d_in[20];
    const float* v_b0    = (const float*)d_in[21];
    const float* v_W1    = (const float*)d_in[22];
    const float* v_b1    = (const float*)d_in[23];
    const float* v_W2    = (const float*)d_in[24];
    const float* v_b2    = (const float*)d_in[25];

    char* ws = (char*)d_ws;
    size_t off = 0;
    auto alloc = [&](size_t bytes) -> char* {
        char* p = ws + off;
        off = (off + bytes + 255) & ~(size_t)255;
        return p;
    };
    float* shT  = (float*)alloc((size_t)128 * BATCH * 4);
    float* soT  = (float*)alloc((size_t)128 * BATCH * 4);
    unsigned short* tT_h = (unsigned short*)alloc((size_t)32 * 163840 * 2);
    unsigned short* tT_o = (unsigned short*)alloc((size_t)32 * 81920 * 2);
    unsigned short* eR   = (unsigned short*)alloc((size_t)BATCH * 128 * 2);
    unsigned short* xrT  = (unsigned short*)alloc((size_t)32 * BATCH * 2);
    float* chT  = (float*)alloc((size_t)32 * BATCH * 4);
    float* coT  = (float*)alloc((size_t)32 * BATCH * 4);
    unsigned short* s2hT = (unsigned short*)alloc((size_t)32 * BATCH * 2);
    unsigned short* s2oT = (unsigned short*)alloc((size_t)32 * BATCH * 2);
    float* bcat = (float*)alloc(96 * 4);
    float* bc2  = (float*)alloc(128 * 4);
    unsigned short* W0b_h = (unsigned short*)alloc(2048 * 2);
    unsigned short* W0b_o = (unsigned short*)alloc(2048 * 2);
    unsigned short* W0b_r = (unsigned short*)alloc(2048 * 2);
    unsigned short* W1f_h = (unsigned short*)alloc(32768 * 2);
    unsigned short* W1f_o = (unsigned short*)alloc(32768 * 2);
    unsigned short* W1f_r = (unsigned short*)alloc(32768 * 2);
    unsigned short* Mf_h  = (unsigned short*)alloc(4096 * 2);
    unsigned short* Mf_o  = (unsigned short*)alloc(4096 * 2);
    unsigned short* Wcatf = (unsigned short*)alloc(36864 * 2);
    unsigned short* Wc2f  = (unsigned short*)alloc(12288 * 2);
    unsigned short* vW0f  = (unsigned short*)alloc(32768 * 2);
    unsigned short* vW1f  = (unsigned short*)alloc(32768 * 2);
    (void)ws_size; (void)in_sizes; (void)n_in; (void)out_size;

    hipMemsetAsync(shT, 0, (size_t)2 * 128 * BATCH * 4, stream);

    k_prep<<<64, 256, 0, stream>>>(c1_relW, c1_relb, c1_rootW, c2_relW, c2_relb, c2_rootW,
                                   wh_W0, wh_W1, wo_W0, wo_W1, wr_W0, wr_W1, v_W0, v_W1,
                                   bcat, bc2, W0b_h, W0b_o, W0b_r, W1f_h, W1f_o, W1f_r,
                                   Mf_h, Mf_o, Wcatf, Wc2f, vW0f, vW1f);

    k_mlpB<<<248, 512, 0, stream>>>(state,
                                    W0b_h, wh_b0, W1f_h, wh_b1, Mf_h, tT_h, shT,
                                    W0b_o, wo_b0, W1f_o, wo_b1, Mf_o, tT_o, soT,
                                    W0b_r, wr_b0, W1f_r, wr_b1, eR);
    k_u2<<<256, 256, 0, stream>>>(eR, shT, soT, Wcatf, bcat, xrT, chT, coT);
    k_sM<<<2048, 256, 0, stream>>>(tT_h, tT_o, chT, coT, s2hT, s2oT);
    k_v<<<256, 256, 0, stream>>>(xrT, s2hT, s2oT, Wc2f, bc2, vW0f, v_b0, vW1f, v_b1,
                                 v_W2, v_b2, (float*)d_out);
}